// Round 10
// baseline (219.557 us; speedup 1.0000x reference)
//
#include <hip/hip_runtime.h>
#include <hip/hip_bf16.h>

// B=8 S=256 H=768 D=128 L=64, all inputs f32.
// Outputs: relate_score (8*64) | lm_b (8*64*128) | lc_b (8*64*128*128), f32.
// k4 processes TWO (b,l) problems per block (same b, l pair) to fill latency-bound phases.

#define PITCH 132
// LDS float offsets
#define AM0   0
#define AM1   16896
#define WB0   33792
#define WB1   35904
#define SSQ   38016   /* [2][256] */
#define SVR   38528   /* [128] shared (depends on b only) */
#define VR    38656   /* vrow [2][128] */
#define ZV    38912   /* [2][128] */
#define ZD    39168   /* [2][128] */
#define LABS  39424   /* [8] */
#define RED   39432   /* [32] */
#define SH_FLOATS 39464

typedef __attribute__((ext_vector_type(8))) short bf16x8;
typedef __attribute__((ext_vector_type(4))) float f32x4;

__device__ __forceinline__ float bf2f(unsigned int u) {
    union { unsigned int i; float f; } c; c.i = u << 16; return c.f;
}
__device__ __forceinline__ unsigned short f2bf(float f) {
    __hip_bfloat16 h = __float2bfloat16(f);
    union { __hip_bfloat16 h; unsigned short u; } c; c.h = h; return c.u;
}

// ---------------------------------------------------------------- K1: wm/wv GEMM (+ bf16 wv^T) + sm/sv (blockIdx.x==128)
__global__ __launch_bounds__(256, 2)
void k1_gemm(const float* __restrict__ Am, const float* __restrict__ Av,
             const float* __restrict__ sfm, const float* __restrict__ sfd,
             const float* __restrict__ W1, const float* __restrict__ B1,
             const float* __restrict__ W2, const float* __restrict__ B2,
             const float* __restrict__ W3, const float* __restrict__ B3,
             const float* __restrict__ W4, const float* __restrict__ B4,
             float* __restrict__ wm, float* __restrict__ wv,
             float* __restrict__ sm, float* __restrict__ sv,
             unsigned short* __restrict__ wvTg) {
    __shared__ float At[16][64];
    __shared__ __align__(16) float Wt[64][128];
    __shared__ float tileT[16][129];
    const int tid = threadIdx.x;
    const int sel = blockIdx.y;
    const bool sentB = (blockIdx.x == 128);
    const float* A  = sentB ? (sel ? sfd : sfm) : (sel ? Av : Am);
    const float* W  = sentB ? (sel ? W4 : W3) : (sel ? W2 : W1);
    const float* Bs = sentB ? (sel ? B4 : B3) : (sel ? B2 : B1);
    float* D = sentB ? (sel ? sv : sm) : (sel ? wv : wm);
    const int R0 = sentB ? 0 : blockIdx.x * 16;
    const int r = tid >> 4;
    const int j0 = (tid & 15) * 8;
    float acc[8] = {0.f,0.f,0.f,0.f,0.f,0.f,0.f,0.f};
    for (int k0 = 0; k0 < 768; k0 += 64) {
        __syncthreads();
#pragma unroll
        for (int it = 0; it < 4; ++it) {
            int f = tid + it * 256;
            int rr = f >> 6, cc = f & 63;
            int rsrc = sentB ? (rr & 7) : rr;
            At[rr][cc] = A[(size_t)(R0 + rsrc) * 768 + k0 + cc];
        }
#pragma unroll
        for (int it = 0; it < 8; ++it) {
            int f = tid + it * 256;
            int rr = f >> 5, c4 = (f & 31) * 4;
            *(float4*)&Wt[rr][c4] = *(const float4*)&W[(size_t)(k0 + rr) * 128 + c4];
        }
        __syncthreads();
#pragma unroll 8
        for (int kk = 0; kk < 64; ++kk) {
            float a = At[r][kk];
            float4 w0 = *(const float4*)&Wt[kk][j0];
            float4 w1 = *(const float4*)&Wt[kk][j0 + 4];
            acc[0] += a * w0.x; acc[1] += a * w0.y; acc[2] += a * w0.z; acc[3] += a * w0.w;
            acc[4] += a * w1.x; acc[5] += a * w1.y; acc[6] += a * w1.z; acc[7] += a * w1.w;
        }
    }
    if (!sentB || r < 8) {
        size_t ob = (size_t)(R0 + r) * 128 + j0;
#pragma unroll
        for (int c = 0; c < 8; ++c) {
            float vl = acc[c] + Bs[j0 + c];
            D[ob + c] = vl;
            tileT[r][j0 + c] = vl;
        }
    }
    if (sel && !sentB) {
        __syncthreads();
        int d = tid >> 1, h = tid & 1;
        unsigned short u[8];
#pragma unroll
        for (int ss = 0; ss < 8; ++ss) u[ss] = f2bf(tileT[h * 8 + ss][d]);
        unsigned int p0 = (unsigned int)u[0] | ((unsigned int)u[1] << 16);
        unsigned int p1 = (unsigned int)u[2] | ((unsigned int)u[3] << 16);
        unsigned int p2 = (unsigned int)u[4] | ((unsigned int)u[5] << 16);
        unsigned int p3 = (unsigned int)u[6] | ((unsigned int)u[7] << 16);
        unsigned short* dst = wvTg + (size_t)(R0 >> 8) * 32768 + (size_t)d * 256 + (R0 & 255) + h * 8;
        *(uint4*)dst = make_uint4(p0, p1, p2, p3);
    }
}

// ---------------------------------------------------------------- dual-problem block reduce: waves 0-1 = prob 0, waves 2-3 = prob 1
template <int N>
__device__ __forceinline__ void bsum2(float* v, float* red) {
#pragma unroll
    for (int o = 32; o; o >>= 1)
#pragma unroll
        for (int n = 0; n < N; ++n) v[n] += __shfl_xor(v[n], o);
    __syncthreads();
    if ((threadIdx.x & 63) == 0) {
        int w = threadIdx.x >> 6;
#pragma unroll
        for (int n = 0; n < N; ++n) red[w * N + n] = v[n];
    }
    __syncthreads();
    int h = threadIdx.x >> 7;
#pragma unroll
    for (int n = 0; n < N; ++n)
        v[n] = red[(2 * h) * N + n] + red[(2 * h + 1) * N + n];
    __syncthreads();
}

// ---------------------------------------------------------------- K4: dual-problem fused kernel. grid 256 (b = bid>>5, l = 2*(bid&31)+{0,1}).
__global__ __launch_bounds__(256, 2)
void k4_fused(const float* __restrict__ wm, const float* __restrict__ wv,
              const unsigned short* __restrict__ wvTg,
              const float* __restrict__ smg, const float* __restrict__ svg,
              const float* __restrict__ lmg, const float* __restrict__ ldvg,
              float* __restrict__ out) {
    extern __shared__ float smem[];
    float* red  = smem + RED;
    float* labs = smem + LABS;

    const int tid = threadIdx.x;
    const int bid = blockIdx.x;
    const int b = bid >> 5;
    const int l0 = (bid & 31) * 2;

    if (tid < 128) {
        smem[SVR + tid] = svg[b * 128 + tid];
        smem[VR + tid]        = ldvg[(size_t)l0 * 128 + tid];
        smem[VR + 128 + tid]  = ldvg[(size_t)(l0 + 1) * 128 + tid];
        smem[ZV + tid]        = lmg[(size_t)l0 * 128 + tid];        // mu0 (temp)
        smem[ZV + 128 + tid]  = lmg[(size_t)(l0 + 1) * 128 + tid];  // mu1 (temp)
    }
    __syncthreads();
    // ---- early output writes (depend only on lmg/vrow)
#pragma unroll
    for (int p2 = 0; p2 < 2; ++p2) {
        const int l_ = l0 + p2;
        const float* vr = smem + VR + p2 * 128;
        if (tid < 32) {
            float4 v = *(const float4*)&lmg[(size_t)l_ * 128 + tid * 4];
            *(float4*)&out[512 + (size_t)(b * 64 + l_) * 128 + tid * 4] = v;
        }
        float* lcb = out + 512 + 65536 + (size_t)(b * 64 + l_) * 16384;
#pragma unroll
        for (int q = 0; q < 16; ++q) {
            int flat4 = q * 256 + tid;
            int i = flat4 >> 5;
            int j4 = (flat4 & 31) * 4;
            float vi = vr[i];
            float4 r;
            r.x = vi * vr[j4 + 0] + ((i == j4 + 0) ? 1.f : 0.f);
            r.y = vi * vr[j4 + 1] + ((i == j4 + 1) ? 1.f : 0.f);
            r.z = vi * vr[j4 + 2] + ((i == j4 + 2) ? 1.f : 0.f);
            r.w = vi * vr[j4 + 3] + ((i == j4 + 3) ? 1.f : 0.f);
            *(float4*)&lcb[(size_t)flat4 * 4] = r;
        }
    }
    // ---- phase 0a: label scalars per problem (h-split), broadcast via labs
    {
        float lv[3] = {0.f, 0.f, 0.f};
        int t = tid & 127, h = tid >> 7;
        float m = smem[ZV + h * 128 + t], v = smem[VR + h * 128 + t];
        lv[0] = m * m; lv[1] = v * v; lv[2] = m * v;
        bsum2<3>(lv, red);
        if ((tid & 127) == 0) {
            int hh = tid >> 7;
            labs[hh * 3 + 0] = lv[0]; labs[hh * 3 + 1] = lv[1]; labs[hh * 3 + 2] = lv[2];
        }
    }
    __syncthreads();
    const float mmp0 = labs[0], np0 = 1.f + labs[1], vmp0 = labs[2];
    const float mmp1 = labs[3], np1 = 1.f + labs[4], vmp1 = labs[5];
    // ---- phase 0b: per-row dots (thread = s), both labels from one row read
    float logit0, logit1;
    {
        const float4* wmr = (const float4*)(wm + (size_t)(b * 256 + tid) * 128);
        const float4* wvr = (const float4*)(wv + (size_t)(b * 256 + tid) * 128);
        const float* mu0 = smem + ZV;       const float* mu1 = smem + ZV + 128;
        const float* vp0 = smem + VR;       const float* vp1 = smem + VR + 128;
        float md0 = 0.f, md1 = 0.f, dot0 = 0.f, dot1 = 0.f;
        float pv0 = 0.f, pv1 = 0.f, vq0 = 0.f, vq1 = 0.f;
        float smm = 0.f, svv = 0.f, smv = 0.f;
#pragma unroll 4
        for (int q = 0; q < 32; ++q) {
            float4 xm = wmr[q], xv = wvr[q];
            const float* m0 = &mu0[q * 4]; const float* m1 = &mu1[q * 4];
            const float* v0 = &vp0[q * 4]; const float* v1 = &vp1[q * 4];
            md0 += m0[0]*xm.x + m0[1]*xm.y + m0[2]*xm.z + m0[3]*xm.w;
            md1 += m1[0]*xm.x + m1[1]*xm.y + m1[2]*xm.z + m1[3]*xm.w;
            dot0 += v0[0]*xv.x + v0[1]*xv.y + v0[2]*xv.z + v0[3]*xv.w;
            dot1 += v1[0]*xv.x + v1[1]*xv.y + v1[2]*xv.z + v1[3]*xv.w;
            pv0 += m0[0]*xv.x + m0[1]*xv.y + m0[2]*xv.z + m0[3]*xv.w;
            pv1 += m1[0]*xv.x + m1[1]*xv.y + m1[2]*xv.z + m1[3]*xv.w;
            vq0 += v0[0]*xm.x + v0[1]*xm.y + v0[2]*xm.z + v0[3]*xm.w;
            vq1 += v1[0]*xm.x + v1[1]*xm.y + v1[2]*xm.z + v1[3]*xm.w;
            smm += xm.x*xm.x + xm.y*xm.y + xm.z*xm.z + xm.w*xm.w;
            svv += xv.x*xv.x + xv.y*xv.y + xv.z*xv.z + xv.w*xv.w;
            smv += xm.x*xv.x + xm.y*xv.y + xm.z*xv.z + xm.w*xv.w;
        }
        float nq = 1.f + svv, inq = 1.f / nq;
        {
            float d2 = smm - 2.f * md0 + mmp0;
            float vqd = smv - pv0, vpd = vq0 - vmp0;
            float inp = 1.f / np0;
            float mq = d2 - vqd * vqd * inq;
            float mp = d2 - vpd * vpd * inp;
            logit0 = 0.25f * ((np0 - 1.f) + (nq - 1.f)
                              - (nq - 1.f + dot0 * dot0) * inq
                              - (np0 - 1.f + dot0 * dot0) * inp + mq + mp);
        }
        {
            float d2 = smm - 2.f * md1 + mmp1;
            float vqd = smv - pv1, vpd = vq1 - vmp1;
            float inp = 1.f / np1;
            float mq = d2 - vqd * vqd * inq;
            float mp = d2 - vpd * vpd * inp;
            logit1 = 0.25f * ((np1 - 1.f) + (nq - 1.f)
                              - (nq - 1.f + dot1 * dot1) * inq
                              - (np1 - 1.f + dot1 * dot1) * inp + mq + mp);
        }
    }
    // ---- phase 0c: dual softmax over 256 threads
    {
        float m0 = logit0, m1 = logit1;
#pragma unroll
        for (int o = 32; o; o >>= 1) {
            m0 = fmaxf(m0, __shfl_xor(m0, o));
            m1 = fmaxf(m1, __shfl_xor(m1, o));
        }
        if ((tid & 63) == 0) { red[tid >> 6] = m0; red[4 + (tid >> 6)] = m1; }
        __syncthreads();
        float mx0 = fmaxf(fmaxf(red[0], red[1]), fmaxf(red[2], red[3]));
        float mx1 = fmaxf(fmaxf(red[4], red[5]), fmaxf(red[6], red[7]));
        float e0 = expf(logit0 - mx0), e1 = expf(logit1 - mx1);
        float s0 = e0, s1 = e1;
#pragma unroll
        for (int o = 32; o; o >>= 1) { s0 += __shfl_xor(s0, o); s1 += __shfl_xor(s1, o); }
        __syncthreads();
        if ((tid & 63) == 0) { red[tid >> 6] = s0; red[4 + (tid >> 6)] = s1; }
        __syncthreads();
        float tot0 = red[0] + red[1] + red[2] + red[3];
        float tot1 = red[4] + red[5] + red[6] + red[7];
        float sc0 = e0 / tot0, sc1 = e1 / tot1;
        smem[AM0 + tid] = sc0;                 // scoreL0 (Amat0 scratch)
        smem[AM1 + tid] = sc1;                 // scoreL1 (Amat1 scratch)
        smem[SSQ + tid] = sqrtf(sc0);
        smem[SSQ + 256 + tid] = sqrtf(sc1);
    }
    __syncthreads();
    // ---- phase 0d: v_mean for both problems (shared wm row reads)
    {
        int d4 = (tid & 31) * 4, sg = tid >> 5;
        const float* wmb = wm + (size_t)b * 256 * 128;
        const float* sc0 = smem + AM0;
        const float* sc1 = smem + AM1;
        float a0x=0.f,a0y=0.f,a0z=0.f,a0w=0.f, a1x=0.f,a1y=0.f,a1z=0.f,a1w=0.f;
        for (int s2 = sg * 32; s2 < sg * 32 + 32; ++s2) {
            float w0 = sc0[s2], w1 = sc1[s2];
            float4 x = *(const float4*)&wmb[(size_t)s2 * 128 + d4];
            a0x += w0 * x.x; a0y += w0 * x.y; a0z += w0 * x.z; a0w += w0 * x.w;
            a1x += w1 * x.x; a1y += w1 * x.y; a1z += w1 * x.z; a1w += w1 * x.w;
        }
        *(float4*)&smem[AM0 + 256 + sg * 128 + d4] = make_float4(a0x, a0y, a0z, a0w);
        *(float4*)&smem[AM1 + 256 + sg * 128 + d4] = make_float4(a1x, a1y, a1z, a1w);
    }
    __syncthreads();
    {
        int t = tid & 127, h = tid >> 7;
        const float* vp = smem + ((h == 0) ? AM0 : AM1) + 256;
        float vm = 0.f;
#pragma unroll
        for (int g2 = 0; g2 < 8; ++g2) vm += vp[g2 * 128 + t];
        smem[ZD + h * 128 + t] = smem[ZV + h * 128 + t]
                               - 0.5f * (smg[b * 128 + t] + vm);   // delta
        smem[ZV + h * 128 + t] = smem[VR + h * 128 + t];           // rhs v
    }
    __syncthreads();   // scratch dead; Amats free for staging
    // ---- phase 1a: stage S^T bf16 for BOTH problems from one raw read
    {
        unsigned short* Sb0 = (unsigned short*)(smem + AM0);
        unsigned short* Sb1 = (unsigned short*)(smem + AM1);
        const unsigned short* src = wvTg + (size_t)b * 32768;
        const int s0 = (tid & 31) * 8;
        float sv0[8], sv1[8];
#pragma unroll
        for (int j = 0; j < 8; ++j) {
            sv0[j] = smem[SSQ + s0 + j];
            sv1[j] = smem[SSQ + 256 + s0 + j];
        }
#pragma unroll
        for (int it = 0; it < 16; ++it) {
            int f8 = tid + it * 256;
            int d = f8 >> 5;
            uint4 raw = *(const uint4*)&src[(size_t)f8 * 8];
            float f[8] = { bf2f(raw.x & 0xffffu), bf2f(raw.x >> 16),
                           bf2f(raw.y & 0xffffu), bf2f(raw.y >> 16),
                           bf2f(raw.z & 0xffffu), bf2f(raw.z >> 16),
                           bf2f(raw.w & 0xffffu), bf2f(raw.w >> 16) };
            uint4 o0, o1;
            o0.x = (unsigned int)f2bf(f[0]*sv0[0]) | ((unsigned int)f2bf(f[1]*sv0[1]) << 16);
            o0.y = (unsigned int)f2bf(f[2]*sv0[2]) | ((unsigned int)f2bf(f[3]*sv0[3]) << 16);
            o0.z = (unsigned int)f2bf(f[4]*sv0[4]) | ((unsigned int)f2bf(f[5]*sv0[5]) << 16);
            o0.w = (unsigned int)f2bf(f[6]*sv0[6]) | ((unsigned int)f2bf(f[7]*sv0[7]) << 16);
            o1.x = (unsigned int)f2bf(f[0]*sv1[0]) | ((unsigned int)f2bf(f[1]*sv1[1]) << 16);
            o1.y = (unsigned int)f2bf(f[2]*sv1[2]) | ((unsigned int)f2bf(f[3]*sv1[3]) << 16);
            o1.z = (unsigned int)f2bf(f[4]*sv1[4]) | ((unsigned int)f2bf(f[5]*sv1[5]) << 16);
            o1.w = (unsigned int)f2bf(f[6]*sv1[6]) | ((unsigned int)f2bf(f[7]*sv1[7]) << 16);
            *(uint4*)&Sb0[(size_t)d * 264 + s0] = o0;
            *(uint4*)&Sb1[(size_t)d * 264 + s0] = o1;
        }
    }
    __syncthreads();
    // ---- phase 1b: M = S^T S via MFMA, per problem (wave w: tile-rows w, w+4)
    {
        const int w = tid >> 6, ln = tid & 63;
        const int rl = ln & 15, g = ln >> 4;
#pragma unroll
        for (int p2 = 0; p2 < 2; ++p2) {
            const unsigned short* Sb = (const unsigned short*)(smem + (p2 ? AM1 : AM0));
            float* Am = smem + (p2 ? AM1 : AM0);
            const int arow0 = 16 * w + rl;
            const int arow1 = 16 * (w + 4) + rl;
            f32x4 acc0[8], acc1[8];
#pragma unroll
            for (int t = 0; t < 8; ++t) {
                acc0[t] = (f32x4){0.f, 0.f, 0.f, 0.f};
                acc1[t] = (f32x4){0.f, 0.f, 0.f, 0.f};
            }
#pragma unroll
            for (int ks = 0; ks < 8; ++ks) {
                bf16x8 a0 = *(const bf16x8*)&Sb[(size_t)arow0 * 264 + ks * 32 + g * 8];
                bf16x8 a1 = *(const bf16x8*)&Sb[(size_t)arow1 * 264 + ks * 32 + g * 8];
#pragma unroll
                for (int tj = 0; tj < 8; ++tj) {
                    bf16x8 bb = *(const bf16x8*)&Sb[(size_t)(16 * tj + rl) * 264 + ks * 32 + g * 8];
                    acc0[tj] = __builtin_amdgcn_mfma_f32_16x16x32_bf16(a0, bb, acc0[tj], 0, 0, 0);
                    acc1[tj] = __builtin_amdgcn_mfma_f32_16x16x32_bf16(a1, bb, acc1[tj], 0, 0, 0);
                }
            }
            __syncthreads();   // all reads of this Sb done; safe to overwrite
#pragma unroll
            for (int tj = 0; tj < 8; ++tj) {
                int j = 16 * tj + rl;
                float svj = smem[SVR + j];
#pragma unroll
                for (int r = 0; r < 4; ++r) {
                    int i = 16 * w + g * 4 + r;
                    Am[i * PITCH + j] = ((i == j) ? 1.f : 0.f)
                                      + 0.5f * (smem[SVR + i] * svj + acc0[tj][r]);
                    int i2 = 16 * (w + 4) + g * 4 + r;
                    Am[i2 * PITCH + j] = ((i2 == j) ? 1.f : 0.f)
                                       + 0.5f * (smem[SVR + i2] * svj + acc1[tj][r]);
                }
            }
        }
    }
    __syncthreads();
    // ---- phase 2c: label-side terms per problem (h-split, 1 thread/row)
    float trP, nv, dds, vds, vsv;
    {
        float v5[5] = {0.f, 0.f, 0.f, 0.f, 0.f};
        int t = tid & 127, h = tid >> 7;
        const float* Am = smem + (h ? AM1 : AM0);
        const float* vr = smem + VR + h * 128;
        v5[0] = Am[t * PITCH + t];
        float vv = vr[t], de = smem[ZD + h * 128 + t];
        v5[1] = vv * vv; v5[2] = de * de; v5[3] = vv * de;
        const float* Ar = &Am[t * PITCH];
        float s2 = 0.f;
        for (int k2 = 0; k2 < 128; k2 += 4) {
            float4 a = *(const float4*)&Ar[k2];
            s2 += a.x * vr[k2] + a.y * vr[k2 + 1] + a.z * vr[k2 + 2] + a.w * vr[k2 + 3];
        }
        v5[4] = vv * s2;
        bsum2<5>(v5, red);
        trP = v5[0]; nv = v5[1]; dds = v5[2]; vds = v5[3]; vsv = v5[4];
    }
    // ---- phase 3: blocked Cholesky with lookahead, both problems per phase
    for (int p = 0; p < 8; ++p) {
        const int base = 16 * p;
        const int R = 112 - base;
        __syncthreads();
        if (p > 0) {
            const int pb = base - 16;
            int t = tid & 127, h = tid >> 7;
            float* Am = smem + (h ? AM1 : AM0);
            float* Wbh = smem + (h ? WB1 : WB0);
            float* zvh = smem + ZV + h * 128;
            float* zdh = smem + ZD + h * 128;
            if (t >= base) {
                int i = t;
                const float* Lr = &Am[i * PITCH + pb];
                float dv = 0.f, dd2 = 0.f;
#pragma unroll
                for (int t2 = 0; t2 < 16; ++t2) {
                    float lvv = Lr[t2];
                    dv  += lvv * zvh[pb + t2];
                    dd2 += lvv * zdh[pb + t2];
                }
                zvh[i] -= dv; zdh[i] -= dd2;
            }
            int njobs = (R + 16) * 16;
            for (int idx = t; idx < njobs; idx += 128) {
                int r2 = idx >> 4, jc = idx & 15;
                int i = base + r2, j = base + jc;
                if (j <= i) {
                    const float* wi = &Wbh[i];
                    const float* wj = &Wbh[j];
                    float acc2 = 0.f;
#pragma unroll
                    for (int t2 = 0; t2 < 16; ++t2)
                        acc2 += wi[t2 * PITCH] * wj[t2 * PITCH];
                    Am[i * PITCH + j] -= acc2;
                }
            }
        }
        __syncthreads();
        if (tid < 128) {
            // F1 for problem (tid>>6): wave 0 -> prob 0, wave 1 -> prob 1
            const int h = tid >> 6, c = tid & 63;
            float* Am = smem + (h ? AM1 : AM0);
            float* zvh = smem + ZV + h * 128;
            float* zdh = smem + ZD + h * 128;
            float cv[16];
            if (c < 16) {
#pragma unroll
                for (int r2 = 0; r2 < 16; ++r2) {
                    int hi = (r2 >= c) ? r2 : c, lo2 = (r2 >= c) ? c : r2;
                    cv[r2] = Am[(base + hi) * PITCH + base + lo2];
                }
            } else {
#pragma unroll
                for (int r2 = 0; r2 < 16; ++r2) cv[r2] = 0.f;
            }
#pragma unroll
            for (int t = 0; t < 16; ++t) {
                float lt[16];
#pragma unroll
                for (int r2 = 0; r2 < 16; ++r2) lt[r2] = __shfl(cv[r2], t);
                float invs = 1.f / sqrtf(lt[t]);
                if (c == t) {
#pragma unroll
                    for (int r2 = 0; r2 < 16; ++r2) cv[r2] = (r2 >= t) ? lt[r2] * invs : 0.f;
                } else if (c > t && c < 16) {
                    float lc = lt[c] * invs;
#pragma unroll
                    for (int r2 = 0; r2 < 16; ++r2)
                        if (r2 > t) cv[r2] -= (lt[r2] * invs) * lc;
                }
            }
            float x[16], acb[16];
#pragma unroll
            for (int r2 = 0; r2 < 16; ++r2) acb[r2] = 0.f;
#pragma unroll
            for (int r2 = 0; r2 < 16; ++r2) {
                float Lrr = __shfl(cv[r2], r2);
                float xr = (((c == r2) ? 1.f : 0.f) - acb[r2]) / Lrr;
                x[r2] = xr;
#pragma unroll
                for (int q = r2 + 1; q < 16; ++q) acb[q] += __shfl(cv[q], r2) * xr;
            }
            if (c < 16) {
#pragma unroll
                for (int r2 = 0; r2 < 16; ++r2)
                    Am[(base + c) * PITCH + base + r2] = x[r2];   // T^T into diag block
            }
            if (c < 32) {
                int t2 = c & 15;
                float* zp = (c < 16) ? zvh : zdh;
                float a0 = 0.f;
#pragma unroll
                for (int a = 0; a < 16; ++a)
                    a0 += Am[(base + a) * PITCH + base + t2] * zp[base + a];
                zp[base + t2] = a0;
            }
        } else if (p > 0 && R > 0) {
            // U_rest from prev panel, both problems (threads 128..255)
            int nt = R >> 3;
            int ntri = (nt * (nt + 1)) >> 1;
            for (int tau2 = tid - 128; tau2 < 2 * ntri; tau2 += 128) {
                int h2 = (tau2 >= ntri) ? 1 : 0;
                int tau = tau2 - h2 * ntri;
                float* Am = smem + (h2 ? AM1 : AM0);
                float* Wbh = smem + (h2 ? WB1 : WB0);
                float ft = sqrtf(8.f * (float)tau + 1.f);
                int tr = (int)((ft - 1.f) * 0.5f);
                while (((tr + 1) * (tr + 2)) / 2 <= tau) ++tr;
                while ((tr * (tr + 1)) / 2 > tau) --tr;
                int tc = tau - ((tr * (tr + 1)) >> 1);
                int ii = base + 16 + tr * 8, jj = base + 16 + tc * 8;
                float a2[8][8];
#pragma unroll
                for (int r2 = 0; r2 < 8; ++r2)
#pragma unroll
                    for (int c2 = 0; c2 < 8; ++c2) a2[r2][c2] = 0.f;
#pragma unroll
                for (int t = 0; t < 16; ++t) {
                    const float* wr = &Wbh[t * PITCH];
                    float4 x0 = *(const float4*)&wr[ii];
                    float4 x1 = *(const float4*)&wr[ii + 4];
                    float4 y0 = *(const float4*)&wr[jj];
                    float4 y1 = *(const float4*)&wr[jj + 4];
                    float xa[8] = {x0.x,x0.y,x0.z,x0.w, x1.x,x1.y,x1.z,x1.w};
                    float yb[8] = {y0.x,y0.y,y0.z,y0.w, y1.x,y1.y,y1.z,y1.w};
#pragma unroll
                    for (int r2 = 0; r2 < 8; ++r2)
#pragma unroll
                        for (int c2 = 0; c2 < 8; ++c2) a2[r2][c2] += xa[r2] * yb[c2];
                }
#pragma unroll
                for (int r2 = 0; r2 < 8; ++r2) {
                    float* Ar2 = &Am[(ii + r2) * PITCH + jj];
                    float4 u0 = *(float4*)&Ar2[0];
                    float4 u1 = *(float4*)&Ar2[4];
                    u0.x -= a2[r2][0]; u0.y -= a2[r2][1]; u0.z -= a2[r2][2]; u0.w -= a2[r2][3];
                    u1.x -= a2[r2][4]; u1.y -= a2[r2][5]; u1.z -= a2[r2][6]; u1.w -= a2[r2][7];
                    *(float4*)&Ar2[0] = u0;
                    *(float4*)&Ar2[4] = u1;
                }
            }
        }
        __syncthreads();
        if (R > 0) {
            int t = tid & 127, h = tid >> 7;
            if (t < R) {
                float* Am = smem + (h ? AM1 : AM0);
                float* Wbh = smem + (h ? WB1 : WB0);
                int i = base + 16 + t;
                const float* Ar = &Am[i * PITCH + base];
                float4 q0 = *(const float4*)&Ar[0];
                float4 q1 = *(const float4*)&Ar[4];
                float4 q2 = *(const float4*)&Ar[8];
                float4 q3 = *(const float4*)&Ar[12];
                float rA[16] = {q0.x,q0.y,q0.z,q0.w, q1.x,q1.y,q1.z,q1.w,
                                q2.x,q2.y,q2.z,q2.w, q3.x,q3.y,q3.z,q3.w};
                float lo[16];
#pragma unroll
                for (int t2 = 0; t2 < 16; ++t2) lo[t2] = 0.f;
#pragma unroll
                for (int a = 0; a < 16; ++a) {
                    float va = rA[a];
                    const float* Trow = &Am[(base + a) * PITCH + base];
                    float4 t0 = *(const float4*)&Trow[0];
                    float4 t1 = *(const float4*)&Trow[4];
                    float4 t2v = *(const float4*)&Trow[8];
                    float4 t3 = *(const float4*)&Trow[12];
                    lo[0] += va * t0.x; lo[1] += va * t0.y; lo[2] += va * t0.z; lo[3] += va * t0.w;
                    lo[4] += va * t1.x; lo[5] += va * t1.y; lo[6] += va * t1.z; lo[7] += va * t1.w;
                    lo[8] += va * t2v.x; lo[9] += va * t2v.y; lo[10] += va * t2v.z; lo[11] += va * t2v.w;
                    lo[12] += va * t3.x; lo[13] += va * t3.y; lo[14] += va * t3.z; lo[15] += va * t3.w;
                }
                float* Aw = &Am[i * PITCH + base];
                *(float4*)&Aw[0]  = make_float4(lo[0], lo[1], lo[2], lo[3]);
                *(float4*)&Aw[4]  = make_float4(lo[4], lo[5], lo[6], lo[7]);
                *(float4*)&Aw[8]  = make_float4(lo[8], lo[9], lo[10], lo[11]);
                *(float4*)&Aw[12] = make_float4(lo[12], lo[13], lo[14], lo[15]);
#pragma unroll
                for (int t2 = 0; t2 < 16; ++t2) Wbh[t2 * PITCH + i] = lo[t2];
            }
        }
    }
    // ---- phase 3b: X = L^{-1} via 7 block-sweeps, both problems per phase
    for (int s2 = 1; s2 <= 7; ++s2) {
        __syncthreads();
        int npair = 8 - s2;
        int jobs = npair * 16;
        int len = 16 * s2;
        for (int t = tid; t < 2 * jobs; t += 256) {
            int h2 = (t >= jobs) ? 1 : 0;
            int tt = t - h2 * jobs;
            float* Am = smem + (h2 ? AM1 : AM0);
            float* Sb = smem + (h2 ? WB1 : WB0);
            int pr = tt >> 4;
            int ta = (tt >> 2) & 3, tb = tt & 3;
            int i = pr + s2, J = pr;
            const float* u0 = &Am[(16 * i + ta * 4) * PITCH + 16 * J];
            const float* w0 = &Am[(16 * J + tb * 4) * PITCH + 16 * J];
            float a4[4][4];
#pragma unroll
            for (int r2 = 0; r2 < 4; ++r2)
#pragma unroll
                for (int c2 = 0; c2 < 4; ++c2) a4[r2][c2] = 0.f;
            for (int k = 0; k < len; k += 4) {
                float4 ur[4], wr4[4];
#pragma unroll
                for (int r2 = 0; r2 < 4; ++r2) ur[r2] = *(const float4*)&u0[r2 * PITCH + k];
#pragma unroll
                for (int c2 = 0; c2 < 4; ++c2) wr4[c2] = *(const float4*)&w0[c2 * PITCH + k];
#pragma unroll
                for (int r2 = 0; r2 < 4; ++r2)
#pragma unroll
                    for (int c2 = 0; c2 < 4; ++c2)
                        a4[r2][c2] += ur[r2].x * wr4[c2].x + ur[r2].y * wr4[c2].y
                                    + ur[r2].z * wr4[c2].z + ur[r2].w * wr4[c2].w;
            }
#pragma unroll
            for (int r2 = 0; r2 < 4; ++r2)
#pragma unroll
                for (int c2 = 0; c2 < 4; ++c2)
                    Sb[pr * 256 + (ta * 4 + r2) * 16 + tb * 4 + c2] = a4[r2][c2];
        }
        __syncthreads();
        int tot2 = npair * 256;
        for (int idx = tid; idx < 2 * tot2; idx += 256) {
            int h2 = (idx >= tot2) ? 1 : 0;
            int ii2 = idx - h2 * tot2;
            float* Am = smem + (h2 ? AM1 : AM0);
            float* Sb = smem + (h2 ? WB1 : WB0);
            int pr = ii2 >> 8;
            int J = pr, i = pr + s2;
            int cc = (ii2 >> 4) & 15, bb = ii2 & 15;
            float a0 = 0.f;
#pragma unroll
            for (int a = 0; a < 16; ++a)
                a0 += Am[(16 * i + a) * PITCH + 16 * i + cc] * Sb[pr * 256 + a * 16 + bb];
            Am[(16 * J + bb) * PITCH + 16 * i + cc] = -a0;
        }
    }
    __syncthreads();
    // ---- phase 4: trinv, qv, qd per problem (h-split, 1 thread/row)
    {
        float v3[3] = {0.f, 0.f, 0.f};
        int t = tid & 127, h = tid >> 7;
        const float* Am = smem + (h ? AM1 : AM0);
        int c0 = (t >> 4) << 4;
        const float* Ar = &Am[t * PITCH];
        for (int k2 = c0; k2 < 128; k2 += 4) {
            float4 a = *(const float4*)&Ar[k2];
            v3[0] += a.x * a.x + a.y * a.y + a.z * a.z + a.w * a.w;
        }
        float a = smem[ZV + h * 128 + t];  v3[1] = a * a;
        float d22 = smem[ZD + h * 128 + t]; v3[2] = d22 * d22;
        bsum2<3>(v3, red);
        if ((tid & 127) == 0) {
            float n = 1.f + nv;
            float Aterm = trP - vsv / n;              // tr(Sq^{-1} Sp)
            float Bt = v3[0] + v3[1];                 // tr(Sp^{-1} Sq)
            float mq = dds - vds * vds / n;           // delta^T Sq^{-1} delta
            out[b * 64 + l0 + h] = 0.25f * (Aterm + Bt - 256.f + mq + v3[2]);
        }
    }
}

// ---------------------------------------------------------------- launch
extern "C" void kernel_launch(void* const* d_in, const int* in_sizes, int n_in,
                              void* d_out, int out_size, void* d_ws, size_t ws_size,
                              hipStream_t stream) {
    const float* wfm = (const float*)d_in[0];
    const float* wfd = (const float*)d_in[1];
    const float* sfm = (const float*)d_in[2];
    const float* sfd = (const float*)d_in[3];
    const float* W1 = (const float*)d_in[4];
    const float* B1 = (const float*)d_in[5];
    const float* W2 = (const float*)d_in[6];
    const float* B2 = (const float*)d_in[7];
    const float* W3 = (const float*)d_in[8];
    const float* B3 = (const float*)d_in[9];
    const float* W4 = (const float*)d_in[10];
    const float* B4 = (const float*)d_in[11];
    const float* lm = (const float*)d_in[12];
    const float* ldv = (const float*)d_in[13];
    float* out = (float*)d_out;
    float* ws = (float*)d_ws;

    float* wm = ws;                           // 262144
    float* wv = ws + 262144;                  // 262144
    float* sm = ws + 524288;                  // 1024
    float* sv = ws + 525312;                  // 1024
    unsigned short* wvTg = (unsigned short*)(ws + 731392);  // 262144 bf16

    constexpr size_t SH_BYTES = (size_t)SH_FLOATS * sizeof(float);  // 157,856 B -> 1 block/CU
    (void)hipFuncSetAttribute((const void*)k4_fused,
                              hipFuncAttributeMaxDynamicSharedMemorySize,
                              (int)SH_BYTES);

    k1_gemm<<<dim3(129, 2), 256, 0, stream>>>(wfm, wfd, sfm, sfd,
                                              W1, B1, W2, B2, W3, B3, W4, B4,
                                              wm, wv, sm, sv, wvTg);
    k4_fused<<<256, 256, SH_BYTES, stream>>>(wm, wv, wvTg, sm, sv, lm, ldv, out);
}

// Round 11
// 190.567 us; speedup vs baseline: 1.1521x; 1.1521x over previous
//
#include <hip/hip_runtime.h>
#include <hip/hip_bf16.h>

// B=8 S=256 H=768 D=128 L=64, all inputs f32.
// Outputs: relate_score (8*64) | lm_b (8*64*128) | lc_b (8*64*128*128), f32.

#define PITCH 132

typedef __attribute__((ext_vector_type(8))) short bf16x8;
typedef __attribute__((ext_vector_type(4))) float f32x4;

__device__ __forceinline__ float bf2f(unsigned int u) {
    union { unsigned int i; float f; } c; c.i = u << 16; return c.f;
}
__device__ __forceinline__ unsigned short f2bf(float f) {
    __hip_bfloat16 h = __float2bfloat16(f);
    union { __hip_bfloat16 h; unsigned short u; } c; c.h = h; return c.u;
}

// ---------------------------------------------------------------- K1: wm/wv GEMM (+ bf16 wv^T) + sm/sv (blockIdx.x==256)
// 8-row x 128-col tiles, grid (257,2) = 514 blocks -> 2 blocks/CU (2 waves/SIMD).
__global__ __launch_bounds__(256, 2)
void k1_gemm(const float* __restrict__ Am, const float* __restrict__ Av,
             const float* __restrict__ sfm, const float* __restrict__ sfd,
             const float* __restrict__ W1, const float* __restrict__ B1,
             const float* __restrict__ W2, const float* __restrict__ B2,
             const float* __restrict__ W3, const float* __restrict__ B3,
             const float* __restrict__ W4, const float* __restrict__ B4,
             float* __restrict__ wm, float* __restrict__ wv,
             float* __restrict__ sm, float* __restrict__ sv,
             unsigned short* __restrict__ wvTg) {
    __shared__ float At[8][64];
    __shared__ __align__(16) float Wt[64][128];
    __shared__ float tileT[8][129];
    const int tid = threadIdx.x;
    const int sel = blockIdx.y;
    const bool sentB = (blockIdx.x == 256);
    const float* A  = sentB ? (sel ? sfd : sfm) : (sel ? Av : Am);
    const float* W  = sentB ? (sel ? W4 : W3) : (sel ? W2 : W1);
    const float* Bs = sentB ? (sel ? B4 : B3) : (sel ? B2 : B1);
    float* D = sentB ? (sel ? sv : sm) : (sel ? wv : wm);
    const int R0 = sentB ? 0 : blockIdx.x * 8;
    const int r = tid >> 5;                 // 0..7
    const int j0 = (tid & 31) * 4;          // 0..124
    float acc[4] = {0.f, 0.f, 0.f, 0.f};
    for (int k0 = 0; k0 < 768; k0 += 64) {
        __syncthreads();
        {   // At: 8x64 = 512 elems, 2 per thread
            int f = tid;
            At[f >> 6][f & 63] = A[(size_t)(R0 + (f >> 6)) * 768 + k0 + (f & 63)];
            f = tid + 256;
            At[f >> 6][f & 63] = A[(size_t)(R0 + (f >> 6)) * 768 + k0 + (f & 63)];
        }
#pragma unroll
        for (int it = 0; it < 8; ++it) {
            int f = tid + it * 256;
            int rr = f >> 5, c4 = (f & 31) * 4;
            *(float4*)&Wt[rr][c4] = *(const float4*)&W[(size_t)(k0 + rr) * 128 + c4];
        }
        __syncthreads();
#pragma unroll 16
        for (int kk = 0; kk < 64; ++kk) {
            float a = At[r][kk];
            float4 w0 = *(const float4*)&Wt[kk][j0];
            acc[0] += a * w0.x; acc[1] += a * w0.y; acc[2] += a * w0.z; acc[3] += a * w0.w;
        }
    }
    {
        float b0 = Bs[j0], b1 = Bs[j0 + 1], b2 = Bs[j0 + 2], b3 = Bs[j0 + 3];
        float4 o = make_float4(acc[0] + b0, acc[1] + b1, acc[2] + b2, acc[3] + b3);
        *(float4*)&D[(size_t)(R0 + r) * 128 + j0] = o;
        tileT[r][j0 + 0] = o.x; tileT[r][j0 + 1] = o.y;
        tileT[r][j0 + 2] = o.z; tileT[r][j0 + 3] = o.w;
    }
    if (sel && !sentB) {   // block-uniform: bf16 transposed copy of this wv tile
        __syncthreads();
        if (tid < 128) {
            int d = tid;
            unsigned short u[8];
#pragma unroll
            for (int ss = 0; ss < 8; ++ss) u[ss] = f2bf(tileT[ss][d]);
            unsigned int p0 = (unsigned int)u[0] | ((unsigned int)u[1] << 16);
            unsigned int p1 = (unsigned int)u[2] | ((unsigned int)u[3] << 16);
            unsigned int p2 = (unsigned int)u[4] | ((unsigned int)u[5] << 16);
            unsigned int p3 = (unsigned int)u[6] | ((unsigned int)u[7] << 16);
            unsigned short* dst = wvTg + (size_t)(R0 >> 8) * 32768 + (size_t)d * 256 + (R0 & 255);
            *(uint4*)dst = make_uint4(p0, p1, p2, p3);
        }
    }
}

// ---------------------------------------------------------------- batched block reduce (4 waves), one barrier set
template <int N>
__device__ __forceinline__ void bsumN(float* v, float* red) {
#pragma unroll
    for (int o = 32; o; o >>= 1)
#pragma unroll
        for (int n = 0; n < N; ++n) v[n] += __shfl_xor(v[n], o);
    __syncthreads();
    if ((threadIdx.x & 63) == 0) {
        int w = threadIdx.x >> 6;
#pragma unroll
        for (int n = 0; n < N; ++n) red[w * N + n] = v[n];
    }
    __syncthreads();
#pragma unroll
    for (int n = 0; n < N; ++n)
        v[n] = red[0 * N + n] + red[1 * N + n] + red[2 * N + n] + red[3 * N + n];
    __syncthreads();
}

// ---------------------------------------------------------------- K4: fully fused; lookahead Cholesky. grid 512 = (b,l), block 256.
__global__ __launch_bounds__(256, 2)
void k4_fused(const float* __restrict__ wm, const float* __restrict__ wv,
              const unsigned short* __restrict__ wvTg,
              const float* __restrict__ smg, const float* __restrict__ svg,
              const float* __restrict__ lmg, const float* __restrict__ ldvg,
              float* __restrict__ out) {
    extern __shared__ float smem[];
    float* Amat = smem;                 // 16896 f32 (pre-stage scratch; S^T bf16 staging; Sigma/L/X)
    float* Wb   = smem + 16896;         // 2112 (Sbuf alias in sweeps)
    float* Sbuf = Wb;
    float* ssq  = smem + 19008;         // 256  sqrt(score)
    float* svr  = smem + 19264;         // 128
    float* vrow = smem + 19392;         // 128  label_div row
    float* zv   = smem + 19520;         // 128  (holds mu=label_mean row until delta is built)
    float* zd   = smem + 19648;         // 128
    float* red  = smem + 19776;         // 24
    float* scoreL = Amat;               // 256 (pre-staging only)
    float* vpart  = Amat + 256;         // 1024 (pre-staging only)

    const int tid = threadIdx.x;
    const int bid = blockIdx.x;
    const int b = bid >> 6, l = bid & 63;

    if (tid < 128) {
        svr[tid]  = svg[b * 128 + tid];
        vrow[tid] = ldvg[l * 128 + tid];
        zv[tid]   = lmg[l * 128 + tid];     // mu (temporary)
    }
    __syncthreads();
    // ---- early output writes: lm_b[b][l], lc_b[b][l]
    if (tid < 32) {
        float4 v = *(const float4*)&lmg[l * 128 + tid * 4];
        *(float4*)&out[512 + (size_t)bid * 128 + tid * 4] = v;
    }
    {
        float* lcb = out + 512 + 65536 + (size_t)bid * 16384;
#pragma unroll
        for (int q = 0; q < 16; ++q) {
            int flat4 = q * 256 + tid;
            int i = flat4 >> 5;
            int j4 = (flat4 & 31) * 4;
            float vi = vrow[i];
            float4 r;
            r.x = vi * vrow[j4 + 0] + ((i == j4 + 0) ? 1.f : 0.f);
            r.y = vi * vrow[j4 + 1] + ((i == j4 + 1) ? 1.f : 0.f);
            r.z = vi * vrow[j4 + 2] + ((i == j4 + 2) ? 1.f : 0.f);
            r.w = vi * vrow[j4 + 3] + ((i == j4 + 3) ? 1.f : 0.f);
            *(float4*)&lcb[(size_t)flat4 * 4] = r;
        }
    }
    // ---- phase 0a: label scalars
    float lv[3] = {0.f, 0.f, 0.f};
    if (tid < 128) {
        float m = zv[tid], v = vrow[tid];
        lv[0] = m * m; lv[1] = v * v; lv[2] = m * v;
    }
    bsumN<3>(lv, red);
    const float mmp = lv[0], np = 1.f + lv[1], vmp = lv[2];
    // ---- phase 0b: per-row dots + row scalars (thread = s)
    const float4* wmr = (const float4*)(wm + (size_t)(b * 256 + tid) * 128);
    const float4* wvr = (const float4*)(wv + (size_t)(b * 256 + tid) * 128);
    float md = 0.f, dot = 0.f, pvv = 0.f, vq = 0.f;
    float smm = 0.f, svv = 0.f, smv = 0.f;
#pragma unroll 8
    for (int q = 0; q < 32; ++q) {
        float4 xm = wmr[q], xv = wvr[q];
        const float* m4 = &zv[q * 4];
        const float* v4 = &vrow[q * 4];
        md  += m4[0] * xm.x + m4[1] * xm.y + m4[2] * xm.z + m4[3] * xm.w;
        dot += v4[0] * xv.x + v4[1] * xv.y + v4[2] * xv.z + v4[3] * xv.w;
        pvv += m4[0] * xv.x + m4[1] * xv.y + m4[2] * xv.z + m4[3] * xv.w;
        vq  += v4[0] * xm.x + v4[1] * xm.y + v4[2] * xm.z + v4[3] * xm.w;
        smm += xm.x * xm.x + xm.y * xm.y + xm.z * xm.z + xm.w * xm.w;
        svv += xv.x * xv.x + xv.y * xv.y + xv.z * xv.z + xv.w * xv.w;
        smv += xm.x * xv.x + xm.y * xv.y + xm.z * xv.z + xm.w * xv.w;
    }
    float nq = 1.f + svv;
    float d2 = smm - 2.f * md + mmp;
    float vqd = smv - pvv, vpd = vq - vmp;
    float inq = 1.f / nq, inp = 1.f / np;
    float maha_q = d2 - vqd * vqd * inq;
    float maha_p = d2 - vpd * vpd * inp;
    float logit = 0.25f * ((np - 1.f) + (nq - 1.f)
                           - (nq - 1.f + dot * dot) * inq
                           - (np - 1.f + dot * dot) * inp
                           + maha_q + maha_p);
    // ---- phase 0c: softmax over 256 threads
    float mx = logit;
#pragma unroll
    for (int o = 32; o; o >>= 1) mx = fmaxf(mx, __shfl_xor(mx, o));
    if ((tid & 63) == 0) red[tid >> 6] = mx;
    __syncthreads();
    mx = fmaxf(fmaxf(red[0], red[1]), fmaxf(red[2], red[3]));
    float e = expf(logit - mx);
    float s = e;
#pragma unroll
    for (int o = 32; o; o >>= 1) s += __shfl_xor(s, o);
    __syncthreads();
    if ((tid & 63) == 0) red[tid >> 6] = s;
    __syncthreads();
    float tot = red[0] + red[1] + red[2] + red[3];
    float sc = e / tot;
    scoreL[tid] = sc;
    ssq[tid] = sqrtf(sc);
    __syncthreads();
    // ---- phase 0d: v_mean = score @ wm
    {
        int d4 = (tid & 31) * 4, sg = tid >> 5;
        const float* wmb = wm + (size_t)b * 256 * 128;
        float ax = 0.f, ay = 0.f, az = 0.f, aw = 0.f;
        for (int s2 = sg * 32; s2 < sg * 32 + 32; ++s2) {
            float w = scoreL[s2];
            float4 x = *(const float4*)&wmb[(size_t)s2 * 128 + d4];
            ax += w * x.x; ay += w * x.y; az += w * x.z; aw += w * x.w;
        }
        *(float4*)&vpart[sg * 128 + d4] = make_float4(ax, ay, az, aw);
    }
    __syncthreads();
    if (tid < 128) {
        float vm8 = 0.f;
#pragma unroll
        for (int g2 = 0; g2 < 8; ++g2) vm8 += vpart[g2 * 128 + tid];
        zd[tid] = zv[tid] - 0.5f * (smg[b * 128 + tid] + vm8);  // delta
        zv[tid] = vrow[tid];                                     // rhs v
    }
    __syncthreads();   // pre-stage scratch dead; Amat free for staging
    // ---- phase 1a: stage S^T (bf16, rows d, 264-bf16 pitch), scaled by sqrt(score)
    {
        unsigned short* Sb = (unsigned short*)Amat;
        const unsigned short* src = wvTg + (size_t)b * 32768;
        const int s0 = (tid & 31) * 8;
        float ssv[8];
#pragma unroll
        for (int j = 0; j < 8; ++j) ssv[j] = ssq[s0 + j];
#pragma unroll
        for (int it = 0; it < 16; ++it) {
            int f8 = tid + it * 256;
            int d = f8 >> 5;
            uint4 raw = *(const uint4*)&src[(size_t)f8 * 8];
            unsigned int p0 = (unsigned int)f2bf(bf2f(raw.x & 0xffffu) * ssv[0])
                            | ((unsigned int)f2bf(bf2f(raw.x >> 16) * ssv[1]) << 16);
            unsigned int p1 = (unsigned int)f2bf(bf2f(raw.y & 0xffffu) * ssv[2])
                            | ((unsigned int)f2bf(bf2f(raw.y >> 16) * ssv[3]) << 16);
            unsigned int p2 = (unsigned int)f2bf(bf2f(raw.z & 0xffffu) * ssv[4])
                            | ((unsigned int)f2bf(bf2f(raw.z >> 16) * ssv[5]) << 16);
            unsigned int p3 = (unsigned int)f2bf(bf2f(raw.w & 0xffffu) * ssv[6])
                            | ((unsigned int)f2bf(bf2f(raw.w >> 16) * ssv[7]) << 16);
            *(uint4*)&Sb[(size_t)d * 264 + s0] = make_uint4(p0, p1, p2, p3);
        }
    }
    __syncthreads();
    // ---- phase 1b: M = S^T S via MFMA; wave w computes tile-rows w and w+4
    {
        const unsigned short* Sb = (const unsigned short*)Amat;
        const int w = tid >> 6, ln = tid & 63;
        const int rl = ln & 15, g = ln >> 4;
        const int arow0 = 16 * w + rl;
        const int arow1 = 16 * (w + 4) + rl;
        f32x4 acc0[8], acc1[8];
#pragma unroll
        for (int t = 0; t < 8; ++t) {
            acc0[t] = (f32x4){0.f, 0.f, 0.f, 0.f};
            acc1[t] = (f32x4){0.f, 0.f, 0.f, 0.f};
        }
#pragma unroll
        for (int ks = 0; ks < 8; ++ks) {
            bf16x8 a0 = *(const bf16x8*)&Sb[(size_t)arow0 * 264 + ks * 32 + g * 8];
            bf16x8 a1 = *(const bf16x8*)&Sb[(size_t)arow1 * 264 + ks * 32 + g * 8];
#pragma unroll
            for (int tj = 0; tj < 8; ++tj) {
                bf16x8 bb = *(const bf16x8*)&Sb[(size_t)(16 * tj + rl) * 264 + ks * 32 + g * 8];
                acc0[tj] = __builtin_amdgcn_mfma_f32_16x16x32_bf16(a0, bb, acc0[tj], 0, 0, 0);
                acc1[tj] = __builtin_amdgcn_mfma_f32_16x16x32_bf16(a1, bb, acc1[tj], 0, 0, 0);
            }
        }
        __syncthreads();   // all MFMA reads done; overwrite with Sigma f32
#pragma unroll
        for (int tj = 0; tj < 8; ++tj) {
            int j = 16 * tj + rl;
            float svj = svr[j];
#pragma unroll
            for (int r = 0; r < 4; ++r) {
                int i = 16 * w + g * 4 + r;
                Amat[i * PITCH + j] = ((i == j) ? 1.f : 0.f) + 0.5f * (svr[i] * svj + acc0[tj][r]);
                int i2 = 16 * (w + 4) + g * 4 + r;
                Amat[i2 * PITCH + j] = ((i2 == j) ? 1.f : 0.f) + 0.5f * (svr[i2] * svj + acc1[tj][r]);
            }
        }
    }
    __syncthreads();
    // ---- phase 2c: label-side closed-form terms, one batched reduction
    float v5[5] = {0.f, 0.f, 0.f, 0.f, 0.f};
    if (tid < 128) {
        v5[0] = Amat[tid * PITCH + tid];
        float vv = vrow[tid], de = zd[tid];
        v5[1] = vv * vv; v5[2] = de * de; v5[3] = vv * de;
    }
    {
        int i = tid >> 1, h = tid & 1;
        const float* Ar = &Amat[i * PITCH + h * 64];
        const float* vr = &vrow[h * 64];
        float s2 = 0.f;
        for (int k2 = 0; k2 < 64; k2 += 4) {
            float4 a = *(const float4*)&Ar[k2];
            s2 += a.x * vr[k2] + a.y * vr[k2 + 1] + a.z * vr[k2 + 2] + a.w * vr[k2 + 3];
        }
        v5[4] = vrow[i] * s2;
    }
    bsumN<5>(v5, red);
    const float trP = v5[0], nv = v5[1], dds = v5[2], vds = v5[3], vsv = v5[4];
    // ---- phase 3: blocked Cholesky with LOOKAHEAD (3 barriers/panel)
    for (int p = 0; p < 8; ++p) {
        const int base = 16 * p;
        const int R = 112 - base;
        __syncthreads();                         // (a) prev panel-solve visible
        if (p > 0) {
            const int pb = base - 16;
            if (tid >= base && tid < 128) {      // z-update from prev panel
                int i = tid;
                const float* Lr = &Amat[i * PITCH + pb];
                float dv = 0.f, dd2 = 0.f;
#pragma unroll
                for (int t = 0; t < 16; ++t) {
                    float lvv = Lr[t];
                    dv  += lvv * zv[pb + t];
                    dd2 += lvv * zd[pb + t];
                }
                zv[i] -= dv; zd[i] -= dd2;
            }
            int njobs = (R + 16) * 16;
            for (int idx = tid; idx < njobs; idx += 256) {
                int r2 = idx >> 4, jc = idx & 15;
                int i = base + r2, j = base + jc;
                if (j <= i) {
                    const float* wi = &Wb[i];
                    const float* wj = &Wb[j];
                    float acc2 = 0.f;
#pragma unroll
                    for (int t2 = 0; t2 < 16; ++t2)
                        acc2 += wi[t2 * PITCH] * wj[t2 * PITCH];
                    Amat[i * PITCH + j] -= acc2;
                }
            }
        }
        __syncthreads();                         // (b) col-panel p fully updated
        if (tid < 64) {
            const int c = tid;
            float cv[16];
            if (c < 16) {
#pragma unroll
                for (int r2 = 0; r2 < 16; ++r2) {
                    int hi = (r2 >= c) ? r2 : c, lo2 = (r2 >= c) ? c : r2;
                    cv[r2] = Amat[(base + hi) * PITCH + base + lo2];
                }
            } else {
#pragma unroll
                for (int r2 = 0; r2 < 16; ++r2) cv[r2] = 0.f;
            }
#pragma unroll
            for (int t = 0; t < 16; ++t) {
                float lt[16];
#pragma unroll
                for (int r2 = 0; r2 < 16; ++r2) lt[r2] = __shfl(cv[r2], t);
                float invs = 1.f / sqrtf(lt[t]);
                if (c == t) {
#pragma unroll
                    for (int r2 = 0; r2 < 16; ++r2) cv[r2] = (r2 >= t) ? lt[r2] * invs : 0.f;
                } else if (c > t && c < 16) {
                    float lc = lt[c] * invs;
#pragma unroll
                    for (int r2 = 0; r2 < 16; ++r2)
                        if (r2 > t) cv[r2] -= (lt[r2] * invs) * lc;
                }
            }
            float x[16], acb[16];
#pragma unroll
            for (int r2 = 0; r2 < 16; ++r2) acb[r2] = 0.f;
#pragma unroll
            for (int r2 = 0; r2 < 16; ++r2) {
                float Lrr = __shfl(cv[r2], r2);
                float xr = (((c == r2) ? 1.f : 0.f) - acb[r2]) / Lrr;
                x[r2] = xr;
#pragma unroll
                for (int q = r2 + 1; q < 16; ++q) acb[q] += __shfl(cv[q], r2) * xr;
            }
            if (c < 16) {
#pragma unroll
                for (int r2 = 0; r2 < 16; ++r2)
                    Amat[(base + c) * PITCH + base + r2] = x[r2];   // T^T into diag block
            }
            if (c < 32) {
                int t2 = c & 15;
                float* zp = (c < 16) ? zv : zd;
                float a0 = 0.f;
#pragma unroll
                for (int a = 0; a < 16; ++a)
                    a0 += Amat[(base + a) * PITCH + base + t2] * zp[base + a];
                zp[base + t2] = a0;
            }
        } else if (p > 0 && R > 0) {
            // U_rest from prev panel: lower 8x8 tiles, rows/cols >= base+16
            int nt = R >> 3;
            int ntri = (nt * (nt + 1)) >> 1;
            for (int tau = tid - 64; tau < ntri; tau += 192) {
                float ft = sqrtf(8.f * (float)tau + 1.f);
                int tr = (int)((ft - 1.f) * 0.5f);
                while (((tr + 1) * (tr + 2)) / 2 <= tau) ++tr;
                while ((tr * (tr + 1)) / 2 > tau) --tr;
                int tc = tau - ((tr * (tr + 1)) >> 1);
                int ii = base + 16 + tr * 8, jj = base + 16 + tc * 8;
                float a2[8][8];
#pragma unroll
                for (int r2 = 0; r2 < 8; ++r2)
#pragma unroll
                    for (int c2 = 0; c2 < 8; ++c2) a2[r2][c2] = 0.f;
#pragma unroll
                for (int t = 0; t < 16; ++t) {
                    const float* wr = &Wb[t * PITCH];
                    float4 x0 = *(const float4*)&wr[ii];
                    float4 x1 = *(const float4*)&wr[ii + 4];
                    float4 y0 = *(const float4*)&wr[jj];
                    float4 y1 = *(const float4*)&wr[jj + 4];
                    float xa[8] = {x0.x,x0.y,x0.z,x0.w, x1.x,x1.y,x1.z,x1.w};
                    float yb[8] = {y0.x,y0.y,y0.z,y0.w, y1.x,y1.y,y1.z,y1.w};
#pragma unroll
                    for (int r2 = 0; r2 < 8; ++r2)
#pragma unroll
                        for (int c2 = 0; c2 < 8; ++c2) a2[r2][c2] += xa[r2] * yb[c2];
                }
#pragma unroll
                for (int r2 = 0; r2 < 8; ++r2) {
                    float* Ar2 = &Amat[(ii + r2) * PITCH + jj];
                    float4 u0 = *(float4*)&Ar2[0];
                    float4 u1 = *(float4*)&Ar2[4];
                    u0.x -= a2[r2][0]; u0.y -= a2[r2][1]; u0.z -= a2[r2][2]; u0.w -= a2[r2][3];
                    u1.x -= a2[r2][4]; u1.y -= a2[r2][5]; u1.z -= a2[r2][6]; u1.w -= a2[r2][7];
                    *(float4*)&Ar2[0] = u0;
                    *(float4*)&Ar2[4] = u1;
                }
            }
        }
        __syncthreads();                         // (c) T ready; Wb(prev) consumed
        if (R > 0 && tid < R) {
            int i = base + 16 + tid;
            const float* Ar = &Amat[i * PITCH + base];
            float4 q0 = *(const float4*)&Ar[0];
            float4 q1 = *(const float4*)&Ar[4];
            float4 q2 = *(const float4*)&Ar[8];
            float4 q3 = *(const float4*)&Ar[12];
            float rA[16] = {q0.x,q0.y,q0.z,q0.w, q1.x,q1.y,q1.z,q1.w,
                            q2.x,q2.y,q2.z,q2.w, q3.x,q3.y,q3.z,q3.w};
            float lo[16];
#pragma unroll
            for (int t = 0; t < 16; ++t) lo[t] = 0.f;
#pragma unroll
            for (int a = 0; a < 16; ++a) {
                float va = rA[a];
                const float* Trow = &Amat[(base + a) * PITCH + base];
                float4 t0 = *(const float4*)&Trow[0];
                float4 t1 = *(const float4*)&Trow[4];
                float4 t2 = *(const float4*)&Trow[8];
                float4 t3 = *(const float4*)&Trow[12];
                lo[0] += va * t0.x; lo[1] += va * t0.y; lo[2] += va * t0.z; lo[3] += va * t0.w;
                lo[4] += va * t1.x; lo[5] += va * t1.y; lo[6] += va * t1.z; lo[7] += va * t1.w;
                lo[8] += va * t2.x; lo[9] += va * t2.y; lo[10] += va * t2.z; lo[11] += va * t2.w;
                lo[12] += va * t3.x; lo[13] += va * t3.y; lo[14] += va * t3.z; lo[15] += va * t3.w;
            }
            float* Aw = &Amat[i * PITCH + base];
            *(float4*)&Aw[0]  = make_float4(lo[0], lo[1], lo[2], lo[3]);
            *(float4*)&Aw[4]  = make_float4(lo[4], lo[5], lo[6], lo[7]);
            *(float4*)&Aw[8]  = make_float4(lo[8], lo[9], lo[10], lo[11]);
            *(float4*)&Aw[12] = make_float4(lo[12], lo[13], lo[14], lo[15]);
#pragma unroll
            for (int t = 0; t < 16; ++t) Wb[t * PITCH + i] = lo[t];
        }
    }
    // ---- phase 3b: X = L^{-1} via 7 block-sweeps; 4x4 register tiles
    for (int s2 = 1; s2 <= 7; ++s2) {
        __syncthreads();
        int npair = 8 - s2;
        int jobs = npair * 16;
        int len = 16 * s2;
        for (int t = tid; t < jobs; t += 256) {
            int pr = t >> 4;
            int ta = (t >> 2) & 3, tb = t & 3;
            int i = pr + s2, J = pr;
            const float* u0 = &Amat[(16 * i + ta * 4) * PITCH + 16 * J];
            const float* w0 = &Amat[(16 * J + tb * 4) * PITCH + 16 * J];
            float a4[4][4];
#pragma unroll
            for (int r2 = 0; r2 < 4; ++r2)
#pragma unroll
                for (int c2 = 0; c2 < 4; ++c2) a4[r2][c2] = 0.f;
            for (int k = 0; k < len; k += 4) {
                float4 ur[4], wr4[4];
#pragma unroll
                for (int r2 = 0; r2 < 4; ++r2) ur[r2] = *(const float4*)&u0[r2 * PITCH + k];
#pragma unroll
                for (int c2 = 0; c2 < 4; ++c2) wr4[c2] = *(const float4*)&w0[c2 * PITCH + k];
#pragma unroll
                for (int r2 = 0; r2 < 4; ++r2)
#pragma unroll
                    for (int c2 = 0; c2 < 4; ++c2)
                        a4[r2][c2] += ur[r2].x * wr4[c2].x + ur[r2].y * wr4[c2].y
                                    + ur[r2].z * wr4[c2].z + ur[r2].w * wr4[c2].w;
            }
#pragma unroll
            for (int r2 = 0; r2 < 4; ++r2)
#pragma unroll
                for (int c2 = 0; c2 < 4; ++c2)
                    Sbuf[pr * 256 + (ta * 4 + r2) * 16 + tb * 4 + c2] = a4[r2][c2];
        }
        __syncthreads();
        for (int idx = tid; idx < npair * 256; idx += 256) {
            int pr = idx >> 8;
            int J = pr, i = pr + s2;
            int cc = (idx >> 4) & 15, bb = idx & 15;
            float a0 = 0.f;
#pragma unroll
            for (int a = 0; a < 16; ++a)
                a0 += Amat[(16 * i + a) * PITCH + 16 * i + cc] * Sbuf[pr * 256 + a * 16 + bb];
            Amat[(16 * J + bb) * PITCH + 16 * i + cc] = -a0;
        }
    }
    __syncthreads();
    // ---- phase 4: trinv, qv, qd (one batched reduction)
    float v3[3] = {0.f, 0.f, 0.f};
    {
        int i = tid & 127, h = tid >> 7;
        int c0 = (i >> 4) << 4;
        int half = (128 - c0) >> 1;
        const float* Ar = &Amat[i * PITCH + c0 + h * half];
        for (int k2 = 0; k2 < half; k2 += 4) {
            float4 a = *(const float4*)&Ar[k2];
            v3[0] += a.x * a.x + a.y * a.y + a.z * a.z + a.w * a.w;
        }
    }
    if (tid < 128) {
        float a = zv[tid];  v3[1] = a * a;
        float d22 = zd[tid]; v3[2] = d22 * d22;
    }
    bsumN<3>(v3, red);
    if (tid == 0) {
        float n = 1.f + nv;
        float Aterm = trP - vsv / n;              // tr(Sq^{-1} Sp)
        float Bt = v3[0] + v3[1];                 // tr(Sp^{-1} Sq)
        float mq = dds - vds * vds / n;           // delta^T Sq^{-1} delta
        out[bid] = 0.25f * (Aterm + Bt - 256.f + mq + v3[2]);
    }
}

// ---------------------------------------------------------------- launch
extern "C" void kernel_launch(void* const* d_in, const int* in_sizes, int n_in,
                              void* d_out, int out_size, void* d_ws, size_t ws_size,
                              hipStream_t stream) {
    const float* wfm = (const float*)d_in[0];
    const float* wfd = (const float*)d_in[1];
    const float* sfm = (const float*)d_in[2];
    const float* sfd = (const float*)d_in[3];
    const float* W1 = (const float*)d_in[4];
    const float* B1 = (const float*)d_in[5];
    const float* W2 = (const float*)d_in[6];
    const float* B2 = (const float*)d_in[7];
    const float* W3 = (const float*)d_in[8];
    const float* B3 = (const float*)d_in[9];
    const float* W4 = (const float*)d_in[10];
    const float* B4 = (const float*)d_in[11];
    const float* lm = (const float*)d_in[12];
    const float* ldv = (const float*)d_in[13];
    float* out = (float*)d_out;
    float* ws = (float*)d_ws;

    float* wm = ws;                           // 262144
    float* wv = ws + 262144;                  // 262144
    float* sm = ws + 524288;                  // 1024
    float* sv = ws + 525312;                  // 1024
    unsigned short* wvTg = (unsigned short*)(ws + 731392);  // 262144 bf16

    constexpr int SH_FLOATS = 19800;
    constexpr size_t SH_BYTES = SH_FLOATS * sizeof(float);   // 79200 B -> 2 blocks/CU
    (void)hipFuncSetAttribute((const void*)k4_fused,
                              hipFuncAttributeMaxDynamicSharedMemorySize,
                              (int)SH_BYTES);

    k1_gemm<<<dim3(257, 2), 256, 0, stream>>>(wfm, wfd, sfm, sfd,
                                              W1, B1, W2, B2, W3, B3, W4, B4,
                                              wm, wv, sm, sv, wvTg);
    k4_fused<<<512, 256, SH_BYTES, stream>>>(wm, wv, wvTg, sm, sv, lm, ldv, out);
}

// Round 12
// 174.197 us; speedup vs baseline: 1.2604x; 1.0940x over previous
//
#include <hip/hip_runtime.h>
#include <hip/hip_bf16.h>

// B=8 S=256 H=768 D=128 L=64, all inputs f32.
// Outputs: relate_score (8*64) | lm_b (8*64*128) | lc_b (8*64*128*128), f32.

#define PITCH 132

typedef __attribute__((ext_vector_type(8))) short bf16x8;
typedef __attribute__((ext_vector_type(4))) float f32x4;

__device__ __forceinline__ float bf2f(unsigned int u) {
    union { unsigned int i; float f; } c; c.i = u << 16; return c.f;
}
__device__ __forceinline__ unsigned short f2bf(float f) {
    __hip_bfloat16 h = __float2bfloat16(f);
    union { __hip_bfloat16 h; unsigned short u; } c; c.h = h; return c.u;
}

// ---------------------------------------------------------------- K1: wm/wv GEMM (+ bf16 wv^T) + sm/sv (x==256) + label scalars (x==257)
__global__ __launch_bounds__(256, 2)
void k1_gemm(const float* __restrict__ Am, const float* __restrict__ Av,
             const float* __restrict__ sfm, const float* __restrict__ sfd,
             const float* __restrict__ W1, const float* __restrict__ B1,
             const float* __restrict__ W2, const float* __restrict__ B2,
             const float* __restrict__ W3, const float* __restrict__ B3,
             const float* __restrict__ W4, const float* __restrict__ B4,
             const float* __restrict__ lm, const float* __restrict__ ldv,
             float* __restrict__ wm, float* __restrict__ wv,
             float* __restrict__ sm, float* __restrict__ sv,
             float4* __restrict__ labscg,
             unsigned short* __restrict__ wvTg) {
    const int tid = threadIdx.x;
    const int sel = blockIdx.y;
    if (blockIdx.x == 257) {           // label scalars: mmp, |v|^2, vmp per label
        if (sel == 0) {
            int l = tid >> 2, q = tid & 3;
            const float* mr = lm + (size_t)l * 128 + q * 32;
            const float* vr = ldv + (size_t)l * 128 + q * 32;
            float s0 = 0.f, s1 = 0.f, s2 = 0.f;
            for (int k = 0; k < 32; k += 4) {
                float4 m = *(const float4*)&mr[k];
                float4 v = *(const float4*)&vr[k];
                s0 += m.x * m.x + m.y * m.y + m.z * m.z + m.w * m.w;
                s1 += v.x * v.x + v.y * v.y + v.z * v.z + v.w * v.w;
                s2 += m.x * v.x + m.y * v.y + m.z * v.z + m.w * v.w;
            }
            s0 += __shfl_xor(s0, 1); s0 += __shfl_xor(s0, 2);
            s1 += __shfl_xor(s1, 1); s1 += __shfl_xor(s1, 2);
            s2 += __shfl_xor(s2, 1); s2 += __shfl_xor(s2, 2);
            if (q == 0) labscg[l] = make_float4(s0, s1, s2, 0.f);
        }
        return;
    }
    __shared__ float At[8][64];
    __shared__ __align__(16) float Wt[64][128];
    __shared__ float tileT[8][129];
    const bool sentB = (blockIdx.x == 256);
    const float* A  = sentB ? (sel ? sfd : sfm) : (sel ? Av : Am);
    const float* W  = sentB ? (sel ? W4 : W3) : (sel ? W2 : W1);
    const float* Bs = sentB ? (sel ? B4 : B3) : (sel ? B2 : B1);
    float* D = sentB ? (sel ? sv : sm) : (sel ? wv : wm);
    const int R0 = sentB ? 0 : blockIdx.x * 8;
    const int r = tid >> 5;
    const int j0 = (tid & 31) * 4;
    float acc[4] = {0.f, 0.f, 0.f, 0.f};
    for (int k0 = 0; k0 < 768; k0 += 64) {
        __syncthreads();
        {
            int f = tid;
            At[f >> 6][f & 63] = A[(size_t)(R0 + (f >> 6)) * 768 + k0 + (f & 63)];
            f = tid + 256;
            At[f >> 6][f & 63] = A[(size_t)(R0 + (f >> 6)) * 768 + k0 + (f & 63)];
        }
#pragma unroll
        for (int it = 0; it < 8; ++it) {
            int f = tid + it * 256;
            int rr = f >> 5, c4 = (f & 31) * 4;
            *(float4*)&Wt[rr][c4] = *(const float4*)&W[(size_t)(k0 + rr) * 128 + c4];
        }
        __syncthreads();
#pragma unroll 16
        for (int kk = 0; kk < 64; ++kk) {
            float a = At[r][kk];
            float4 w0 = *(const float4*)&Wt[kk][j0];
            acc[0] += a * w0.x; acc[1] += a * w0.y; acc[2] += a * w0.z; acc[3] += a * w0.w;
        }
    }
    {
        float b0 = Bs[j0], b1 = Bs[j0 + 1], b2 = Bs[j0 + 2], b3 = Bs[j0 + 3];
        float4 o = make_float4(acc[0] + b0, acc[1] + b1, acc[2] + b2, acc[3] + b3);
        *(float4*)&D[(size_t)(R0 + r) * 128 + j0] = o;
        tileT[r][j0 + 0] = o.x; tileT[r][j0 + 1] = o.y;
        tileT[r][j0 + 2] = o.z; tileT[r][j0 + 3] = o.w;
    }
    if (sel && !sentB) {
        __syncthreads();
        if (tid < 128) {
            int d = tid;
            unsigned short u[8];
#pragma unroll
            for (int ss = 0; ss < 8; ++ss) u[ss] = f2bf(tileT[ss][d]);
            unsigned int p0 = (unsigned int)u[0] | ((unsigned int)u[1] << 16);
            unsigned int p1 = (unsigned int)u[2] | ((unsigned int)u[3] << 16);
            unsigned int p2 = (unsigned int)u[4] | ((unsigned int)u[5] << 16);
            unsigned int p3 = (unsigned int)u[6] | ((unsigned int)u[7] << 16);
            unsigned short* dst = wvTg + (size_t)(R0 >> 8) * 32768 + (size_t)d * 256 + (R0 & 255);
            *(uint4*)dst = make_uint4(p0, p1, p2, p3);
        }
    }
}

// ---------------------------------------------------------------- batched block reduce (4 waves), one barrier set
template <int N>
__device__ __forceinline__ void bsumN(float* v, float* red) {
#pragma unroll
    for (int o = 32; o; o >>= 1)
#pragma unroll
        for (int n = 0; n < N; ++n) v[n] += __shfl_xor(v[n], o);
    __syncthreads();
    if ((threadIdx.x & 63) == 0) {
        int w = threadIdx.x >> 6;
#pragma unroll
        for (int n = 0; n < N; ++n) red[w * N + n] = v[n];
    }
    __syncthreads();
#pragma unroll
    for (int n = 0; n < N; ++n)
        v[n] = red[0 * N + n] + red[1 * N + n] + red[2 * N + n] + red[3 * N + n];
    __syncthreads();
}

// ---------------------------------------------------------------- K4: fused; lookahead Cholesky + recursive-doubling inverse.
__global__ __launch_bounds__(256, 2)
void k4_fused(const float* __restrict__ wm, const float* __restrict__ wv,
              const unsigned short* __restrict__ wvTg,
              const float* __restrict__ smg, const float* __restrict__ svg,
              const float* __restrict__ lmg, const float* __restrict__ ldvg,
              const float4* __restrict__ labscg,
              float* __restrict__ out) {
    extern __shared__ float smem[];
    float* Amat = smem;                 // 16896 f32
    float* Wb   = smem + 16896;         // 2112 (RD temp alias)
    float* ssq  = smem + 19008;         // 256
    float* svr  = smem + 19264;         // 128
    float* vrow = smem + 19392;         // 128
    float* zv   = smem + 19520;         // 128  (mu until delta built)
    float* zd   = smem + 19648;         // 128
    float* red  = smem + 19776;         // 24
    float* scoreL = Amat;               // 256 (pre-staging only)
    float* vpart  = Amat + 256;         // 1024 (pre-staging only)

    const int tid = threadIdx.x;
    const int bid = blockIdx.x;
    const int b = bid >> 6, l = bid & 63;

    if (tid < 128) {
        svr[tid]  = svg[b * 128 + tid];
        vrow[tid] = ldvg[l * 128 + tid];
        zv[tid]   = lmg[l * 128 + tid];     // mu (temporary)
    }
    __syncthreads();
    // ---- early output writes: lm_b[b][l], lc_b[b][l]
    if (tid < 32) {
        float4 v = *(const float4*)&lmg[l * 128 + tid * 4];
        *(float4*)&out[512 + (size_t)bid * 128 + tid * 4] = v;
    }
    {
        float* lcb = out + 512 + 65536 + (size_t)bid * 16384;
#pragma unroll
        for (int q = 0; q < 16; ++q) {
            int flat4 = q * 256 + tid;
            int i = flat4 >> 5;
            int j4 = (flat4 & 31) * 4;
            float vi = vrow[i];
            float4 r;
            r.x = vi * vrow[j4 + 0] + ((i == j4 + 0) ? 1.f : 0.f);
            r.y = vi * vrow[j4 + 1] + ((i == j4 + 1) ? 1.f : 0.f);
            r.z = vi * vrow[j4 + 2] + ((i == j4 + 2) ? 1.f : 0.f);
            r.w = vi * vrow[j4 + 3] + ((i == j4 + 3) ? 1.f : 0.f);
            *(float4*)&lcb[(size_t)flat4 * 4] = r;
        }
    }
    // ---- phase 0a: label scalars (precomputed in k1)
    float4 lsv = labscg[l];
    const float mmp = lsv.x, np = 1.f + lsv.y, vmp = lsv.z;
    // ---- phase 0b: per-row dots + row scalars (thread = s)
    const float4* wmr = (const float4*)(wm + (size_t)(b * 256 + tid) * 128);
    const float4* wvr = (const float4*)(wv + (size_t)(b * 256 + tid) * 128);
    float md = 0.f, dot = 0.f, pvv = 0.f, vq = 0.f;
    float smm = 0.f, svv = 0.f, smv = 0.f;
#pragma unroll 8
    for (int q = 0; q < 32; ++q) {
        float4 xm = wmr[q], xv = wvr[q];
        const float* m4 = &zv[q * 4];
        const float* v4 = &vrow[q * 4];
        md  += m4[0] * xm.x + m4[1] * xm.y + m4[2] * xm.z + m4[3] * xm.w;
        dot += v4[0] * xv.x + v4[1] * xv.y + v4[2] * xv.z + v4[3] * xv.w;
        pvv += m4[0] * xv.x + m4[1] * xv.y + m4[2] * xv.z + m4[3] * xv.w;
        vq  += v4[0] * xm.x + v4[1] * xm.y + v4[2] * xm.z + v4[3] * xm.w;
        smm += xm.x * xm.x + xm.y * xm.y + xm.z * xm.z + xm.w * xm.w;
        svv += xv.x * xv.x + xv.y * xv.y + xv.z * xv.z + xv.w * xv.w;
        smv += xm.x * xv.x + xm.y * xv.y + xm.z * xv.z + xm.w * xv.w;
    }
    float nq = 1.f + svv;
    float d2 = smm - 2.f * md + mmp;
    float vqd = smv - pvv, vpd = vq - vmp;
    float inq = 1.f / nq, inp = 1.f / np;
    float maha_q = d2 - vqd * vqd * inq;
    float maha_p = d2 - vpd * vpd * inp;
    float logit = 0.25f * ((np - 1.f) + (nq - 1.f)
                           - (nq - 1.f + dot * dot) * inq
                           - (np - 1.f + dot * dot) * inp
                           + maha_q + maha_p);
    // ---- phase 0c: softmax over 256 threads
    float mx = logit;
#pragma unroll
    for (int o = 32; o; o >>= 1) mx = fmaxf(mx, __shfl_xor(mx, o));
    if ((tid & 63) == 0) red[tid >> 6] = mx;
    __syncthreads();
    mx = fmaxf(fmaxf(red[0], red[1]), fmaxf(red[2], red[3]));
    float e = expf(logit - mx);
    float s = e;
#pragma unroll
    for (int o = 32; o; o >>= 1) s += __shfl_xor(s, o);
    __syncthreads();
    if ((tid & 63) == 0) red[tid >> 6] = s;
    __syncthreads();
    float tot = red[0] + red[1] + red[2] + red[3];
    float sc = e / tot;
    scoreL[tid] = sc;
    ssq[tid] = sqrtf(sc);
    __syncthreads();
    // ---- phase 0d: v_mean = score @ wm
    {
        int d4 = (tid & 31) * 4, sg = tid >> 5;
        const float* wmb = wm + (size_t)b * 256 * 128;
        float ax = 0.f, ay = 0.f, az = 0.f, aw = 0.f;
        for (int s2 = sg * 32; s2 < sg * 32 + 32; ++s2) {
            float w = scoreL[s2];
            float4 x = *(const float4*)&wmb[(size_t)s2 * 128 + d4];
            ax += w * x.x; ay += w * x.y; az += w * x.z; aw += w * x.w;
        }
        *(float4*)&vpart[sg * 128 + d4] = make_float4(ax, ay, az, aw);
    }
    __syncthreads();
    if (tid < 128) {
        float vm8 = 0.f;
#pragma unroll
        for (int g2 = 0; g2 < 8; ++g2) vm8 += vpart[g2 * 128 + tid];
        zd[tid] = zv[tid] - 0.5f * (smg[b * 128 + tid] + vm8);  // delta
        zv[tid] = vrow[tid];                                     // rhs v
    }
    __syncthreads();
    // ---- phase 1a: stage S^T (bf16, rows d, 264-bf16 pitch), scaled by sqrt(score)
    {
        unsigned short* Sb = (unsigned short*)Amat;
        const unsigned short* src = wvTg + (size_t)b * 32768;
        const int s0 = (tid & 31) * 8;
        float ssv[8];
#pragma unroll
        for (int j = 0; j < 8; ++j) ssv[j] = ssq[s0 + j];
#pragma unroll
        for (int it = 0; it < 16; ++it) {
            int f8 = tid + it * 256;
            int d = f8 >> 5;
            uint4 raw = *(const uint4*)&src[(size_t)f8 * 8];
            unsigned int p0 = (unsigned int)f2bf(bf2f(raw.x & 0xffffu) * ssv[0])
                            | ((unsigned int)f2bf(bf2f(raw.x >> 16) * ssv[1]) << 16);
            unsigned int p1 = (unsigned int)f2bf(bf2f(raw.y & 0xffffu) * ssv[2])
                            | ((unsigned int)f2bf(bf2f(raw.y >> 16) * ssv[3]) << 16);
            unsigned int p2 = (unsigned int)f2bf(bf2f(raw.z & 0xffffu) * ssv[4])
                            | ((unsigned int)f2bf(bf2f(raw.z >> 16) * ssv[5]) << 16);
            unsigned int p3 = (unsigned int)f2bf(bf2f(raw.w & 0xffffu) * ssv[6])
                            | ((unsigned int)f2bf(bf2f(raw.w >> 16) * ssv[7]) << 16);
            *(uint4*)&Sb[(size_t)d * 264 + s0] = make_uint4(p0, p1, p2, p3);
        }
    }
    __syncthreads();
    // ---- phase 1b: M = S^T S via MFMA; wave w computes tile-rows w and w+4
    {
        const unsigned short* Sb = (const unsigned short*)Amat;
        const int w = tid >> 6, ln = tid & 63;
        const int rl = ln & 15, g = ln >> 4;
        const int arow0 = 16 * w + rl;
        const int arow1 = 16 * (w + 4) + rl;
        f32x4 acc0[8], acc1[8];
#pragma unroll
        for (int t = 0; t < 8; ++t) {
            acc0[t] = (f32x4){0.f, 0.f, 0.f, 0.f};
            acc1[t] = (f32x4){0.f, 0.f, 0.f, 0.f};
        }
#pragma unroll
        for (int ks = 0; ks < 8; ++ks) {
            bf16x8 a0 = *(const bf16x8*)&Sb[(size_t)arow0 * 264 + ks * 32 + g * 8];
            bf16x8 a1 = *(const bf16x8*)&Sb[(size_t)arow1 * 264 + ks * 32 + g * 8];
#pragma unroll
            for (int tj = 0; tj < 8; ++tj) {
                bf16x8 bb = *(const bf16x8*)&Sb[(size_t)(16 * tj + rl) * 264 + ks * 32 + g * 8];
                acc0[tj] = __builtin_amdgcn_mfma_f32_16x16x32_bf16(a0, bb, acc0[tj], 0, 0, 0);
                acc1[tj] = __builtin_amdgcn_mfma_f32_16x16x32_bf16(a1, bb, acc1[tj], 0, 0, 0);
            }
        }
        __syncthreads();
#pragma unroll
        for (int tj = 0; tj < 8; ++tj) {
            int j = 16 * tj + rl;
            float svj = svr[j];
#pragma unroll
            for (int r = 0; r < 4; ++r) {
                int i = 16 * w + g * 4 + r;
                Amat[i * PITCH + j] = ((i == j) ? 1.f : 0.f) + 0.5f * (svr[i] * svj + acc0[tj][r]);
                int i2 = 16 * (w + 4) + g * 4 + r;
                Amat[i2 * PITCH + j] = ((i2 == j) ? 1.f : 0.f) + 0.5f * (svr[i2] * svj + acc1[tj][r]);
            }
        }
    }
    __syncthreads();
    // ---- phase 2c: label-side closed-form terms, one batched reduction
    float v5[5] = {0.f, 0.f, 0.f, 0.f, 0.f};
    if (tid < 128) {
        v5[0] = Amat[tid * PITCH + tid];
        float vv = vrow[tid], de = zd[tid];
        v5[1] = vv * vv; v5[2] = de * de; v5[3] = vv * de;
    }
    {
        int i = tid >> 1, h = tid & 1;
        const float* Ar = &Amat[i * PITCH + h * 64];
        const float* vr = &vrow[h * 64];
        float s2 = 0.f;
        for (int k2 = 0; k2 < 64; k2 += 4) {
            float4 a = *(const float4*)&Ar[k2];
            s2 += a.x * vr[k2] + a.y * vr[k2 + 1] + a.z * vr[k2 + 2] + a.w * vr[k2 + 3];
        }
        v5[4] = vrow[i] * s2;
    }
    bsumN<5>(v5, red);
    const float trP = v5[0], nv = v5[1], dds = v5[2], vds = v5[3], vsv = v5[4];
    // ---- phase 3: blocked Cholesky with LOOKAHEAD (3 barriers/panel)
    for (int p = 0; p < 8; ++p) {
        const int base = 16 * p;
        const int R = 112 - base;
        __syncthreads();
        if (p > 0) {
            const int pb = base - 16;
            if (tid >= base && tid < 128) {
                int i = tid;
                const float* Lr = &Amat[i * PITCH + pb];
                float dv = 0.f, dd2 = 0.f;
#pragma unroll
                for (int t = 0; t < 16; ++t) {
                    float lvv = Lr[t];
                    dv  += lvv * zv[pb + t];
                    dd2 += lvv * zd[pb + t];
                }
                zv[i] -= dv; zd[i] -= dd2;
            }
            int njobs = (R + 16) * 16;
            for (int idx = tid; idx < njobs; idx += 256) {
                int r2 = idx >> 4, jc = idx & 15;
                int i = base + r2, j = base + jc;
                if (j <= i) {
                    const float* wi = &Wb[i];
                    const float* wj = &Wb[j];
                    float acc2 = 0.f;
#pragma unroll
                    for (int t2 = 0; t2 < 16; ++t2)
                        acc2 += wi[t2 * PITCH] * wj[t2 * PITCH];
                    Amat[i * PITCH + j] -= acc2;
                }
            }
        }
        __syncthreads();
        if (tid < 64) {
            const int c = tid;
            float cv[16];
            if (c < 16) {
#pragma unroll
                for (int r2 = 0; r2 < 16; ++r2) {
                    int hi = (r2 >= c) ? r2 : c, lo2 = (r2 >= c) ? c : r2;
                    cv[r2] = Amat[(base + hi) * PITCH + base + lo2];
                }
            } else {
#pragma unroll
                for (int r2 = 0; r2 < 16; ++r2) cv[r2] = 0.f;
            }
#pragma unroll
            for (int t = 0; t < 16; ++t) {
                float lt[16];
#pragma unroll
                for (int r2 = 0; r2 < 16; ++r2) lt[r2] = __shfl(cv[r2], t);
                float invs = 1.f / sqrtf(lt[t]);
                if (c == t) {
#pragma unroll
                    for (int r2 = 0; r2 < 16; ++r2) cv[r2] = (r2 >= t) ? lt[r2] * invs : 0.f;
                } else if (c > t && c < 16) {
                    float lc = lt[c] * invs;
#pragma unroll
                    for (int r2 = 0; r2 < 16; ++r2)
                        if (r2 > t) cv[r2] -= (lt[r2] * invs) * lc;
                }
            }
            float x[16], acb[16];
#pragma unroll
            for (int r2 = 0; r2 < 16; ++r2) acb[r2] = 0.f;
#pragma unroll
            for (int r2 = 0; r2 < 16; ++r2) {
                float Lrr = __shfl(cv[r2], r2);
                float xr = (((c == r2) ? 1.f : 0.f) - acb[r2]) / Lrr;
                x[r2] = xr;
#pragma unroll
                for (int q = r2 + 1; q < 16; ++q) acb[q] += __shfl(cv[q], r2) * xr;
            }
            if (c < 16) {
#pragma unroll
                for (int r2 = 0; r2 < 16; ++r2)
                    Amat[(base + c) * PITCH + base + r2] = x[r2];   // T^T into diag block
            }
            if (c < 32) {
                int t2 = c & 15;
                float* zp = (c < 16) ? zv : zd;
                float a0 = 0.f;
#pragma unroll
                for (int a = 0; a < 16; ++a)
                    a0 += Amat[(base + a) * PITCH + base + t2] * zp[base + a];
                zp[base + t2] = a0;
            }
        } else if (p > 0 && R > 0) {
            int nt = R >> 3;
            int ntri = (nt * (nt + 1)) >> 1;
            for (int tau = tid - 64; tau < ntri; tau += 192) {
                float ft = sqrtf(8.f * (float)tau + 1.f);
                int tr = (int)((ft - 1.f) * 0.5f);
                while (((tr + 1) * (tr + 2)) / 2 <= tau) ++tr;
                while ((tr * (tr + 1)) / 2 > tau) --tr;
                int tc = tau - ((tr * (tr + 1)) >> 1);
                int ii = base + 16 + tr * 8, jj = base + 16 + tc * 8;
                float a2[8][8];
#pragma unroll
                for (int r2 = 0; r2 < 8; ++r2)
#pragma unroll
                    for (int c2 = 0; c2 < 8; ++c2) a2[r2][c2] = 0.f;
#pragma unroll
                for (int t = 0; t < 16; ++t) {
                    const float* wr = &Wb[t * PITCH];
                    float4 x0 = *(const float4*)&wr[ii];
                    float4 x1 = *(const float4*)&wr[ii + 4];
                    float4 y0 = *(const float4*)&wr[jj];
                    float4 y1 = *(const float4*)&wr[jj + 4];
                    float xa[8] = {x0.x,x0.y,x0.z,x0.w, x1.x,x1.y,x1.z,x1.w};
                    float yb[8] = {y0.x,y0.y,y0.z,y0.w, y1.x,y1.y,y1.z,y1.w};
#pragma unroll
                    for (int r2 = 0; r2 < 8; ++r2)
#pragma unroll
                        for (int c2 = 0; c2 < 8; ++c2) a2[r2][c2] += xa[r2] * yb[c2];
                }
#pragma unroll
                for (int r2 = 0; r2 < 8; ++r2) {
                    float* Ar2 = &Amat[(ii + r2) * PITCH + jj];
                    float4 u0 = *(float4*)&Ar2[0];
                    float4 u1 = *(float4*)&Ar2[4];
                    u0.x -= a2[r2][0]; u0.y -= a2[r2][1]; u0.z -= a2[r2][2]; u0.w -= a2[r2][3];
                    u1.x -= a2[r2][4]; u1.y -= a2[r2][5]; u1.z -= a2[r2][6]; u1.w -= a2[r2][7];
                    *(float4*)&Ar2[0] = u0;
                    *(float4*)&Ar2[4] = u1;
                }
            }
        }
        __syncthreads();
        if (R > 0 && tid < R) {
            int i = base + 16 + tid;
            const float* Ar = &Amat[i * PITCH + base];
            float4 q0 = *(const float4*)&Ar[0];
            float4 q1 = *(const float4*)&Ar[4];
            float4 q2 = *(const float4*)&Ar[8];
            float4 q3 = *(const float4*)&Ar[12];
            float rA[16] = {q0.x,q0.y,q0.z,q0.w, q1.x,q1.y,q1.z,q1.w,
                            q2.x,q2.y,q2.z,q2.w, q3.x,q3.y,q3.z,q3.w};
            float lo[16];
#pragma unroll
            for (int t = 0; t < 16; ++t) lo[t] = 0.f;
#pragma unroll
            for (int a = 0; a < 16; ++a) {
                float va = rA[a];
                const float* Trow = &Amat[(base + a) * PITCH + base];
                float4 t0 = *(const float4*)&Trow[0];
                float4 t1 = *(const float4*)&Trow[4];
                float4 t2 = *(const float4*)&Trow[8];
                float4 t3 = *(const float4*)&Trow[12];
                lo[0] += va * t0.x; lo[1] += va * t0.y; lo[2] += va * t0.z; lo[3] += va * t0.w;
                lo[4] += va * t1.x; lo[5] += va * t1.y; lo[6] += va * t1.z; lo[7] += va * t1.w;
                lo[8] += va * t2.x; lo[9] += va * t2.y; lo[10] += va * t2.z; lo[11] += va * t2.w;
                lo[12] += va * t3.x; lo[13] += va * t3.y; lo[14] += va * t3.z; lo[15] += va * t3.w;
            }
            float* Aw = &Amat[i * PITCH + base];
            *(float4*)&Aw[0]  = make_float4(lo[0], lo[1], lo[2], lo[3]);
            *(float4*)&Aw[4]  = make_float4(lo[4], lo[5], lo[6], lo[7]);
            *(float4*)&Aw[8]  = make_float4(lo[8], lo[9], lo[10], lo[11]);
            *(float4*)&Aw[12] = make_float4(lo[12], lo[13], lo[14], lo[15]);
#pragma unroll
            for (int t = 0; t < 16; ++t) Wb[t * PITCH + i] = lo[t];
        }
    }
    // ---- phase 3b: X = L^{-1} via RECURSIVE DOUBLING (16 -> 32 -> 64 -> 128).
    // Read rule: X[rg][cg] = Amat[cg*PITCH+rg] (block(rg)>=block(cg); T blocks store zeros above diag);
    //            L[rg][cg] = Amat[rg*PITCH+cg] (strictly-lower 16-blocks, never overwritten).
    __syncthreads();
    // Level 1: X(J+1,J) = -T_{J+1} L(J+1,J) T_J, pairs q=0..3 (J=2q)
    for (int t = tid; t < 128; t += 256) {   // step A: Yt = (L21*T1)^T -> Wb[q*256 + c*16 + r]
        int q = t >> 5, tt = t & 31;
        int c0 = (tt >> 2) * 2, r0 = (tt & 3) * 4;
        int rb = 32 * q + 16, cb = 32 * q;
        float a4[2][4] = {{0,0,0,0},{0,0,0,0}};
        for (int k = 0; k < 16; k += 4) {
            float4 xc0 = *(const float4*)&Amat[(cb + c0) * PITCH + cb + k];
            float4 xc1 = *(const float4*)&Amat[(cb + c0 + 1) * PITCH + cb + k];
#pragma unroll
            for (int rr = 0; rr < 4; ++rr) {
                float4 lr = *(const float4*)&Amat[(rb + r0 + rr) * PITCH + cb + k];
                a4[0][rr] += xc0.x * lr.x + xc0.y * lr.y + xc0.z * lr.z + xc0.w * lr.w;
                a4[1][rr] += xc1.x * lr.x + xc1.y * lr.y + xc1.z * lr.z + xc1.w * lr.w;
            }
        }
#pragma unroll
        for (int cc = 0; cc < 2; ++cc)
#pragma unroll
            for (int rr = 0; rr < 4; ++rr)
                Wb[q * 256 + (c0 + cc) * 16 + (r0 + rr)] = a4[cc][rr];
    }
    __syncthreads();
    for (int t = tid; t < 128; t += 256) {   // step B: X21^T = -(Yt * T2^T)
        int q = t >> 5, tt = t & 31;
        int c0 = (tt >> 2) * 2, r0 = (tt & 3) * 4;
        int rb = 32 * q + 16, cb = 32 * q;
        float a4[2][4] = {{0,0,0,0},{0,0,0,0}};
        for (int a = 0; a < 16; ++a) {
            float y0 = Wb[q * 256 + c0 * 16 + a];
            float y1 = Wb[q * 256 + (c0 + 1) * 16 + a];
            float4 t2 = *(const float4*)&Amat[(rb + a) * PITCH + rb + r0];
            a4[0][0] += y0 * t2.x; a4[0][1] += y0 * t2.y; a4[0][2] += y0 * t2.z; a4[0][3] += y0 * t2.w;
            a4[1][0] += y1 * t2.x; a4[1][1] += y1 * t2.y; a4[1][2] += y1 * t2.z; a4[1][3] += y1 * t2.w;
        }
#pragma unroll
        for (int cc = 0; cc < 2; ++cc)
#pragma unroll
            for (int rr = 0; rr < 4; ++rr)
                Amat[(cb + c0 + cc) * PITCH + rb + r0 + rr] = -a4[cc][rr];
    }
    __syncthreads();
    // Level 2: 32-super-pairs q=0..1: X21(32) = -X2 L21 X1
    {   // step A -> Wb[q*1024 + c*32 + r]
        int q = tid >> 7, tt = tid & 127;
        int c0 = (tt >> 3) * 2, r0 = (tt & 7) * 4;
        int rb = 64 * q + 32, cb = 64 * q;
        int ks = c0 & ~15;
        float a4[2][4] = {{0,0,0,0},{0,0,0,0}};
        for (int k = ks; k < 32; k += 4) {
            float4 xc0 = *(const float4*)&Amat[(cb + c0) * PITCH + cb + k];
            float4 xc1 = *(const float4*)&Amat[(cb + c0 + 1) * PITCH + cb + k];
#pragma unroll
            for (int rr = 0; rr < 4; ++rr) {
                float4 lr = *(const float4*)&Amat[(rb + r0 + rr) * PITCH + cb + k];
                a4[0][rr] += xc0.x * lr.x + xc0.y * lr.y + xc0.z * lr.z + xc0.w * lr.w;
                a4[1][rr] += xc1.x * lr.x + xc1.y * lr.y + xc1.z * lr.z + xc1.w * lr.w;
            }
        }
#pragma unroll
        for (int cc = 0; cc < 2; ++cc)
#pragma unroll
            for (int rr = 0; rr < 4; ++rr)
                Wb[q * 1024 + (c0 + cc) * 32 + (r0 + rr)] = a4[cc][rr];
    }
    __syncthreads();
    {   // step B
        int q = tid >> 7, tt = tid & 127;
        int c0 = (tt >> 3) * 2, r0 = (tt & 7) * 4;
        int rb = 64 * q + 32, cb = 64 * q;
        int atop = (r0 & ~15) + 15;
        float a4[2][4] = {{0,0,0,0},{0,0,0,0}};
        for (int a = 0; a <= atop; ++a) {
            float y0 = Wb[q * 1024 + c0 * 32 + a];
            float y1 = Wb[q * 1024 + (c0 + 1) * 32 + a];
            float4 t2 = *(const float4*)&Amat[(rb + a) * PITCH + rb + r0];
            a4[0][0] += y0 * t2.x; a4[0][1] += y0 * t2.y; a4[0][2] += y0 * t2.z; a4[0][3] += y0 * t2.w;
            a4[1][0] += y1 * t2.x; a4[1][1] += y1 * t2.y; a4[1][2] += y1 * t2.z; a4[1][3] += y1 * t2.w;
        }
#pragma unroll
        for (int cc = 0; cc < 2; ++cc)
#pragma unroll
            for (int rr = 0; rr < 4; ++rr)
                Amat[(cb + c0 + cc) * PITCH + rb + r0 + rr] = -a4[cc][rr];
    }
    __syncthreads();
    // Level 3: 64-pair (rows 64-127, cols 0-63), two column halves
#pragma unroll
    for (int h3 = 0; h3 < 2; ++h3) {
        const int ch = 32 * h3;
        {   // step A: Yt[c][r] -> Wb[c*64 + r], c 0..31 (global col ch+c), r 0..63
            int c0 = (tid >> 4) * 2, r0 = (tid & 15) * 4;
            int ks = (ch + c0) & ~15;
            float a4[2][4] = {{0,0,0,0},{0,0,0,0}};
            for (int k = ks; k < 64; k += 4) {
                float4 xc0 = *(const float4*)&Amat[(ch + c0) * PITCH + k];
                float4 xc1 = *(const float4*)&Amat[(ch + c0 + 1) * PITCH + k];
#pragma unroll
                for (int rr = 0; rr < 4; ++rr) {
                    float4 lr = *(const float4*)&Amat[(64 + r0 + rr) * PITCH + k];
                    a4[0][rr] += xc0.x * lr.x + xc0.y * lr.y + xc0.z * lr.z + xc0.w * lr.w;
                    a4[1][rr] += xc1.x * lr.x + xc1.y * lr.y + xc1.z * lr.z + xc1.w * lr.w;
                }
            }
#pragma unroll
            for (int cc = 0; cc < 2; ++cc)
#pragma unroll
                for (int rr = 0; rr < 4; ++rr)
                    Wb[(c0 + cc) * 64 + r0 + rr] = a4[cc][rr];
        }
        __syncthreads();
        {   // step B
            int c0 = (tid >> 4) * 2, r0 = (tid & 15) * 4;
            int atop = (r0 & ~15) + 15;
            float a4[2][4] = {{0,0,0,0},{0,0,0,0}};
            for (int a = 0; a <= atop; ++a) {
                float y0 = Wb[c0 * 64 + a];
                float y1 = Wb[(c0 + 1) * 64 + a];
                float4 t2 = *(const float4*)&Amat[(64 + a) * PITCH + 64 + r0];
                a4[0][0] += y0 * t2.x; a4[0][1] += y0 * t2.y; a4[0][2] += y0 * t2.z; a4[0][3] += y0 * t2.w;
                a4[1][0] += y1 * t2.x; a4[1][1] += y1 * t2.y; a4[1][2] += y1 * t2.z; a4[1][3] += y1 * t2.w;
            }
#pragma unroll
            for (int cc = 0; cc < 2; ++cc)
#pragma unroll
                for (int rr = 0; rr < 4; ++rr)
                    Amat[(ch + c0 + cc) * PITCH + 64 + r0 + rr] = -a4[cc][rr];
        }
        __syncthreads();
    }
    // ---- phase 4: trinv, qv, qd (one batched reduction)
    float v3[3] = {0.f, 0.f, 0.f};
    {
        int i = tid & 127, h = tid >> 7;
        int c0 = (i >> 4) << 4;
        int half = (128 - c0) >> 1;
        const float* Ar = &Amat[i * PITCH + c0 + h * half];
        for (int k2 = 0; k2 < half; k2 += 4) {
            float4 a = *(const float4*)&Ar[k2];
            v3[0] += a.x * a.x + a.y * a.y + a.z * a.z + a.w * a.w;
        }
    }
    if (tid < 128) {
        float a = zv[tid];  v3[1] = a * a;
        float d22 = zd[tid]; v3[2] = d22 * d22;
    }
    bsumN<3>(v3, red);
    if (tid == 0) {
        float n = 1.f + nv;
        float Aterm = trP - vsv / n;              // tr(Sq^{-1} Sp)
        float Bt = v3[0] + v3[1];                 // tr(Sp^{-1} Sq)
        float mq = dds - vds * vds / n;           // delta^T Sq^{-1} delta
        out[bid] = 0.25f * (Aterm + Bt - 256.f + mq + v3[2]);
    }
}

// ---------------------------------------------------------------- launch
extern "C" void kernel_launch(void* const* d_in, const int* in_sizes, int n_in,
                              void* d_out, int out_size, void* d_ws, size_t ws_size,
                              hipStream_t stream) {
    const float* wfm = (const float*)d_in[0];
    const float* wfd = (const float*)d_in[1];
    const float* sfm = (const float*)d_in[2];
    const float* sfd = (const float*)d_in[3];
    const float* W1 = (const float*)d_in[4];
    const float* B1 = (const float*)d_in[5];
    const float* W2 = (const float*)d_in[6];
    const float* B2 = (const float*)d_in[7];
    const float* W3 = (const float*)d_in[8];
    const float* B3 = (const float*)d_in[9];
    const float* W4 = (const float*)d_in[10];
    const float* B4 = (const float*)d_in[11];
    const float* lm = (const float*)d_in[12];
    const float* ldv = (const float*)d_in[13];
    float* out = (float*)d_out;
    float* ws = (float*)d_ws;

    float* wm = ws;                           // 262144
    float* wv = ws + 262144;                  // 262144
    float* sm = ws + 524288;                  // 1024
    float* sv = ws + 525312;                  // 1024
    float4* labscg = (float4*)(ws + 526336);  // 64 float4
    unsigned short* wvTg = (unsigned short*)(ws + 731392);  // 262144 bf16

    constexpr int SH_FLOATS = 19800;
    constexpr size_t SH_BYTES = SH_FLOATS * sizeof(float);   // 79200 B -> 2 blocks/CU
    (void)hipFuncSetAttribute((const void*)k4_fused,
                              hipFuncAttributeMaxDynamicSharedMemorySize,
                              (int)SH_BYTES);

    k1_gemm<<<dim3(258, 2), 256, 0, stream>>>(wfm, wfd, sfm, sfd,
                                              W1, B1, W2, B2, W3, B3, W4, B4,
                                              lm, ldv, wm, wv, sm, sv, labscg, wvTg);
    k4_fused<<<512, 256, SH_BYTES, stream>>>(wm, wv, wvTg, sm, sv, lm, ldv, labscg, out);
}

// Round 13
// 173.504 us; speedup vs baseline: 1.2654x; 1.0040x over previous
//
#include <hip/hip_runtime.h>
#include <hip/hip_bf16.h>

// B=8 S=256 H=768 D=128 L=64, all inputs f32.
// Outputs: relate_score (8*64) | lm_b (8*64*128) | lc_b (8*64*128*128), f32.

#define PITCH 132

typedef __attribute__((ext_vector_type(8))) short bf16x8;
typedef __attribute__((ext_vector_type(4))) float f32x4;

__device__ __forceinline__ float bf2f(unsigned int u) {
    union { unsigned int i; float f; } c; c.i = u << 16; return c.f;
}
__device__ __forceinline__ unsigned short f2bf(float f) {
    __hip_bfloat16 h = __float2bfloat16(f);
    union { __hip_bfloat16 h; unsigned short u; } c; c.h = h; return c.u;
}

// ---------------------------------------------------------------- K1: wm/wv GEMM (+ bf16 wv^T) + sm/sv (x==256) + label scalars (x==257)
__global__ __launch_bounds__(256, 2)
void k1_gemm(const float* __restrict__ Am, const float* __restrict__ Av,
             const float* __restrict__ sfm, const float* __restrict__ sfd,
             const float* __restrict__ W1, const float* __restrict__ B1,
             const float* __restrict__ W2, const float* __restrict__ B2,
             const float* __restrict__ W3, const float* __restrict__ B3,
             const float* __restrict__ W4, const float* __restrict__ B4,
             const float* __restrict__ lm, const float* __restrict__ ldv,
             float* __restrict__ wm, float* __restrict__ wv,
             float* __restrict__ sm, float* __restrict__ sv,
             float4* __restrict__ labscg,
             unsigned short* __restrict__ wvTg) {
    const int tid = threadIdx.x;
    const int sel = blockIdx.y;
    if (blockIdx.x == 257) {           // label scalars: mmp, |v|^2, vmp per label
        if (sel == 0) {
            int l = tid >> 2, q = tid & 3;
            const float* mr = lm + (size_t)l * 128 + q * 32;
            const float* vr = ldv + (size_t)l * 128 + q * 32;
            float s0 = 0.f, s1 = 0.f, s2 = 0.f;
            for (int k = 0; k < 32; k += 4) {
                float4 m = *(const float4*)&mr[k];
                float4 v = *(const float4*)&vr[k];
                s0 += m.x * m.x + m.y * m.y + m.z * m.z + m.w * m.w;
                s1 += v.x * v.x + v.y * v.y + v.z * v.z + v.w * v.w;
                s2 += m.x * v.x + m.y * v.y + m.z * v.z + m.w * v.w;
            }
            s0 += __shfl_xor(s0, 1); s0 += __shfl_xor(s0, 2);
            s1 += __shfl_xor(s1, 1); s1 += __shfl_xor(s1, 2);
            s2 += __shfl_xor(s2, 1); s2 += __shfl_xor(s2, 2);
            if (q == 0) labscg[l] = make_float4(s0, s1, s2, 0.f);
        }
        return;
    }
    __shared__ float At[8][64];
    __shared__ __align__(16) float Wt[64][128];
    __shared__ float tileT[8][129];
    const bool sentB = (blockIdx.x == 256);
    const float* A  = sentB ? (sel ? sfd : sfm) : (sel ? Av : Am);
    const float* W  = sentB ? (sel ? W4 : W3) : (sel ? W2 : W1);
    const float* Bs = sentB ? (sel ? B4 : B3) : (sel ? B2 : B1);
    float* D = sentB ? (sel ? sv : sm) : (sel ? wv : wm);
    const int R0 = sentB ? 0 : blockIdx.x * 8;
    const int r = tid >> 5;
    const int j0 = (tid & 31) * 4;
    float acc[4] = {0.f, 0.f, 0.f, 0.f};
    for (int k0 = 0; k0 < 768; k0 += 64) {
        __syncthreads();
        {
            int f = tid;
            At[f >> 6][f & 63] = A[(size_t)(R0 + (f >> 6)) * 768 + k0 + (f & 63)];
            f = tid + 256;
            At[f >> 6][f & 63] = A[(size_t)(R0 + (f >> 6)) * 768 + k0 + (f & 63)];
        }
#pragma unroll
        for (int it = 0; it < 8; ++it) {
            int f = tid + it * 256;
            int rr = f >> 5, c4 = (f & 31) * 4;
            *(float4*)&Wt[rr][c4] = *(const float4*)&W[(size_t)(k0 + rr) * 128 + c4];
        }
        __syncthreads();
#pragma unroll 16
        for (int kk = 0; kk < 64; ++kk) {
            float a = At[r][kk];
            float4 w0 = *(const float4*)&Wt[kk][j0];
            acc[0] += a * w0.x; acc[1] += a * w0.y; acc[2] += a * w0.z; acc[3] += a * w0.w;
        }
    }
    {
        float b0 = Bs[j0], b1 = Bs[j0 + 1], b2 = Bs[j0 + 2], b3 = Bs[j0 + 3];
        float4 o = make_float4(acc[0] + b0, acc[1] + b1, acc[2] + b2, acc[3] + b3);
        *(float4*)&D[(size_t)(R0 + r) * 128 + j0] = o;
        tileT[r][j0 + 0] = o.x; tileT[r][j0 + 1] = o.y;
        tileT[r][j0 + 2] = o.z; tileT[r][j0 + 3] = o.w;
    }
    if (sel && !sentB) {
        __syncthreads();
        if (tid < 128) {
            int d = tid;
            unsigned short u[8];
#pragma unroll
            for (int ss = 0; ss < 8; ++ss) u[ss] = f2bf(tileT[ss][d]);
            unsigned int p0 = (unsigned int)u[0] | ((unsigned int)u[1] << 16);
            unsigned int p1 = (unsigned int)u[2] | ((unsigned int)u[3] << 16);
            unsigned int p2 = (unsigned int)u[4] | ((unsigned int)u[5] << 16);
            unsigned int p3 = (unsigned int)u[6] | ((unsigned int)u[7] << 16);
            unsigned short* dst = wvTg + (size_t)(R0 >> 8) * 32768 + (size_t)d * 256 + (R0 & 255);
            *(uint4*)dst = make_uint4(p0, p1, p2, p3);
        }
    }
}

// ---------------------------------------------------------------- batched block reduce (4 waves), one barrier set
template <int N>
__device__ __forceinline__ void bsumN(float* v, float* red) {
#pragma unroll
    for (int o = 32; o; o >>= 1)
#pragma unroll
        for (int n = 0; n < N; ++n) v[n] += __shfl_xor(v[n], o);
    __syncthreads();
    if ((threadIdx.x & 63) == 0) {
        int w = threadIdx.x >> 6;
#pragma unroll
        for (int n = 0; n < N; ++n) red[w * N + n] = v[n];
    }
    __syncthreads();
#pragma unroll
    for (int n = 0; n < N; ++n)
        v[n] = red[0 * N + n] + red[1 * N + n] + red[2 * N + n] + red[3 * N + n];
    __syncthreads();
}

// ---------------------------------------------------------------- K4: fused; 2-barrier lookahead Cholesky + recursive-doubling inverse.
__global__ __launch_bounds__(256, 2)
void k4_fused(const float* __restrict__ wm, const float* __restrict__ wv,
              const unsigned short* __restrict__ wvTg,
              const float* __restrict__ smg, const float* __restrict__ svg,
              const float* __restrict__ lmg, const float* __restrict__ ldvg,
              const float4* __restrict__ labscg,
              float* __restrict__ out) {
    extern __shared__ float smem[];
    float* Amat = smem;                 // 16896 f32
    float* Wb   = smem + 16896;         // 2112 (RD temp alias)
    float* ssq  = smem + 19008;         // 256
    float* svr  = smem + 19264;         // 128
    float* vrow = smem + 19392;         // 128
    float* zv   = smem + 19520;         // 128  (mu until delta built)
    float* zd   = smem + 19648;         // 128
    float* red  = smem + 19776;         // 24
    float* scoreL = Amat;               // 256 (pre-staging only)
    float* vpart  = Amat + 256;         // 1024 (pre-staging only)

    const int tid = threadIdx.x;
    const int bid = blockIdx.x;
    const int b = bid >> 6, l = bid & 63;

    if (tid < 128) {
        svr[tid]  = svg[b * 128 + tid];
        vrow[tid] = ldvg[l * 128 + tid];
        zv[tid]   = lmg[l * 128 + tid];     // mu (temporary)
    }
    __syncthreads();
    // ---- early output writes: lm_b[b][l], lc_b[b][l]
    if (tid < 32) {
        float4 v = *(const float4*)&lmg[l * 128 + tid * 4];
        *(float4*)&out[512 + (size_t)bid * 128 + tid * 4] = v;
    }
    {
        float* lcb = out + 512 + 65536 + (size_t)bid * 16384;
#pragma unroll
        for (int q = 0; q < 16; ++q) {
            int flat4 = q * 256 + tid;
            int i = flat4 >> 5;
            int j4 = (flat4 & 31) * 4;
            float vi = vrow[i];
            float4 r;
            r.x = vi * vrow[j4 + 0] + ((i == j4 + 0) ? 1.f : 0.f);
            r.y = vi * vrow[j4 + 1] + ((i == j4 + 1) ? 1.f : 0.f);
            r.z = vi * vrow[j4 + 2] + ((i == j4 + 2) ? 1.f : 0.f);
            r.w = vi * vrow[j4 + 3] + ((i == j4 + 3) ? 1.f : 0.f);
            *(float4*)&lcb[(size_t)flat4 * 4] = r;
        }
    }
    // ---- phase 0a: label scalars (precomputed in k1)
    float4 lsv = labscg[l];
    const float mmp = lsv.x, np = 1.f + lsv.y, vmp = lsv.z;
    // ---- phase 0b: per-row dots + row scalars (thread = s)
    const float4* wmr = (const float4*)(wm + (size_t)(b * 256 + tid) * 128);
    const float4* wvr = (const float4*)(wv + (size_t)(b * 256 + tid) * 128);
    float md = 0.f, dot = 0.f, pvv = 0.f, vq = 0.f;
    float smm = 0.f, svv = 0.f, smv = 0.f;
#pragma unroll 8
    for (int q = 0; q < 32; ++q) {
        float4 xm = wmr[q], xv = wvr[q];
        const float* m4 = &zv[q * 4];
        const float* v4 = &vrow[q * 4];
        md  += m4[0] * xm.x + m4[1] * xm.y + m4[2] * xm.z + m4[3] * xm.w;
        dot += v4[0] * xv.x + v4[1] * xv.y + v4[2] * xv.z + v4[3] * xv.w;
        pvv += m4[0] * xv.x + m4[1] * xv.y + m4[2] * xv.z + m4[3] * xv.w;
        vq  += v4[0] * xm.x + v4[1] * xm.y + v4[2] * xm.z + v4[3] * xm.w;
        smm += xm.x * xm.x + xm.y * xm.y + xm.z * xm.z + xm.w * xm.w;
        svv += xv.x * xv.x + xv.y * xv.y + xv.z * xv.z + xv.w * xv.w;
        smv += xm.x * xv.x + xm.y * xv.y + xm.z * xv.z + xm.w * xv.w;
    }
    float nq = 1.f + svv;
    float d2 = smm - 2.f * md + mmp;
    float vqd = smv - pvv, vpd = vq - vmp;
    float inq = 1.f / nq, inp = 1.f / np;
    float maha_q = d2 - vqd * vqd * inq;
    float maha_p = d2 - vpd * vpd * inp;
    float logit = 0.25f * ((np - 1.f) + (nq - 1.f)
                           - (nq - 1.f + dot * dot) * inq
                           - (np - 1.f + dot * dot) * inp
                           + maha_q + maha_p);
    // ---- phase 0c: softmax over 256 threads (2 barriers: distinct red slots)
    float mx = logit;
#pragma unroll
    for (int o = 32; o; o >>= 1) mx = fmaxf(mx, __shfl_xor(mx, o));
    if ((tid & 63) == 0) red[tid >> 6] = mx;
    __syncthreads();
    mx = fmaxf(fmaxf(red[0], red[1]), fmaxf(red[2], red[3]));
    float e = expf(logit - mx);
    float s = e;
#pragma unroll
    for (int o = 32; o; o >>= 1) s += __shfl_xor(s, o);
    if ((tid & 63) == 0) red[8 + (tid >> 6)] = s;
    __syncthreads();
    float tot = red[8] + red[9] + red[10] + red[11];
    float sc = e / tot;
    scoreL[tid] = sc;
    ssq[tid] = sqrtf(sc);
    __syncthreads();
    // ---- phase 0d: v_mean = score @ wm
    {
        int d4 = (tid & 31) * 4, sg = tid >> 5;
        const float* wmb = wm + (size_t)b * 256 * 128;
        float ax = 0.f, ay = 0.f, az = 0.f, aw = 0.f;
        for (int s2 = sg * 32; s2 < sg * 32 + 32; ++s2) {
            float w = scoreL[s2];
            float4 x = *(const float4*)&wmb[(size_t)s2 * 128 + d4];
            ax += w * x.x; ay += w * x.y; az += w * x.z; aw += w * x.w;
        }
        *(float4*)&vpart[sg * 128 + d4] = make_float4(ax, ay, az, aw);
    }
    __syncthreads();
    if (tid < 128) {
        float vm8 = 0.f;
#pragma unroll
        for (int g2 = 0; g2 < 8; ++g2) vm8 += vpart[g2 * 128 + tid];
        zd[tid] = zv[tid] - 0.5f * (smg[b * 128 + tid] + vm8);  // delta
        zv[tid] = vrow[tid];                                     // rhs v
    }
    __syncthreads();
    // ---- phase 1a: stage S^T (bf16, rows d, 264-bf16 pitch), scaled by sqrt(score)
    {
        unsigned short* Sb = (unsigned short*)Amat;
        const unsigned short* src = wvTg + (size_t)b * 32768;
        const int s0 = (tid & 31) * 8;
        float ssv[8];
#pragma unroll
        for (int j = 0; j < 8; ++j) ssv[j] = ssq[s0 + j];
#pragma unroll
        for (int it = 0; it < 16; ++it) {
            int f8 = tid + it * 256;
            int d = f8 >> 5;
            uint4 raw = *(const uint4*)&src[(size_t)f8 * 8];
            unsigned int p0 = (unsigned int)f2bf(bf2f(raw.x & 0xffffu) * ssv[0])
                            | ((unsigned int)f2bf(bf2f(raw.x >> 16) * ssv[1]) << 16);
            unsigned int p1 = (unsigned int)f2bf(bf2f(raw.y & 0xffffu) * ssv[2])
                            | ((unsigned int)f2bf(bf2f(raw.y >> 16) * ssv[3]) << 16);
            unsigned int p2 = (unsigned int)f2bf(bf2f(raw.z & 0xffffu) * ssv[4])
                            | ((unsigned int)f2bf(bf2f(raw.z >> 16) * ssv[5]) << 16);
            unsigned int p3 = (unsigned int)f2bf(bf2f(raw.w & 0xffffu) * ssv[6])
                            | ((unsigned int)f2bf(bf2f(raw.w >> 16) * ssv[7]) << 16);
            *(uint4*)&Sb[(size_t)d * 264 + s0] = make_uint4(p0, p1, p2, p3);
        }
    }
    __syncthreads();
    // ---- phase 1b: M = S^T S via MFMA; wave w computes tile-rows w and w+4
    {
        const unsigned short* Sb = (const unsigned short*)Amat;
        const int w = tid >> 6, ln = tid & 63;
        const int rl = ln & 15, g = ln >> 4;
        const int arow0 = 16 * w + rl;
        const int arow1 = 16 * (w + 4) + rl;
        f32x4 acc0[8], acc1[8];
#pragma unroll
        for (int t = 0; t < 8; ++t) {
            acc0[t] = (f32x4){0.f, 0.f, 0.f, 0.f};
            acc1[t] = (f32x4){0.f, 0.f, 0.f, 0.f};
        }
#pragma unroll
        for (int ks = 0; ks < 8; ++ks) {
            bf16x8 a0 = *(const bf16x8*)&Sb[(size_t)arow0 * 264 + ks * 32 + g * 8];
            bf16x8 a1 = *(const bf16x8*)&Sb[(size_t)arow1 * 264 + ks * 32 + g * 8];
#pragma unroll
            for (int tj = 0; tj < 8; ++tj) {
                bf16x8 bb = *(const bf16x8*)&Sb[(size_t)(16 * tj + rl) * 264 + ks * 32 + g * 8];
                acc0[tj] = __builtin_amdgcn_mfma_f32_16x16x32_bf16(a0, bb, acc0[tj], 0, 0, 0);
                acc1[tj] = __builtin_amdgcn_mfma_f32_16x16x32_bf16(a1, bb, acc1[tj], 0, 0, 0);
            }
        }
        __syncthreads();
#pragma unroll
        for (int tj = 0; tj < 8; ++tj) {
            int j = 16 * tj + rl;
            float svj = svr[j];
#pragma unroll
            for (int r = 0; r < 4; ++r) {
                int i = 16 * w + g * 4 + r;
                Amat[i * PITCH + j] = ((i == j) ? 1.f : 0.f) + 0.5f * (svr[i] * svj + acc0[tj][r]);
                int i2 = 16 * (w + 4) + g * 4 + r;
                Amat[i2 * PITCH + j] = ((i2 == j) ? 1.f : 0.f) + 0.5f * (svr[i2] * svj + acc1[tj][r]);
            }
        }
    }
    __syncthreads();
    // ---- phase 2c: label-side closed-form terms, one batched reduction
    float v5[5] = {0.f, 0.f, 0.f, 0.f, 0.f};
    if (tid < 128) {
        v5[0] = Amat[tid * PITCH + tid];
        float vv = vrow[tid], de = zd[tid];
        v5[1] = vv * vv; v5[2] = de * de; v5[3] = vv * de;
    }
    {
        int i = tid >> 1, h = tid & 1;
        const float* Ar = &Amat[i * PITCH + h * 64];
        const float* vr = &vrow[h * 64];
        float s2 = 0.f;
        for (int k2 = 0; k2 < 64; k2 += 4) {
            float4 a = *(const float4*)&Ar[k2];
            s2 += a.x * vr[k2] + a.y * vr[k2 + 1] + a.z * vr[k2 + 2] + a.w * vr[k2 + 3];
        }
        v5[4] = vrow[i] * s2;
    }
    bsumN<5>(v5, red);
    const float trP = v5[0], nv = v5[1], dds = v5[2], vds = v5[3], vsv = v5[4];
    // ---- phase 3: blocked Cholesky, 2 barriers/panel.
    // (b): wave0 F1 (diag self-corrected in regs from Wb(p-1)) ||
    //      waves1-3: z-trailing update + U_col-below + U_rest (all from panel p-1)
    // (c): panel solve (tid<R) || z' transform (wave 2, threads 128..159)
    for (int p = 0; p < 8; ++p) {
        const int base = 16 * p;
        const int R = 112 - base;
        __syncthreads();                         // solve(p-1)/Wb(p-1)/z'(p-1) visible
        if (tid < 64) {
            const int c = tid;
            float cv[16];
            if (c < 16) {
#pragma unroll
                for (int r2 = 0; r2 < 16; ++r2) {
                    int hi = (r2 >= c) ? r2 : c, lo2 = (r2 >= c) ? c : r2;
                    cv[r2] = Amat[(base + hi) * PITCH + base + lo2];
                }
                if (p > 0) {
                    float wbc[16];
#pragma unroll
                    for (int t = 0; t < 16; ++t) wbc[t] = Wb[t * PITCH + base + c];
#pragma unroll
                    for (int r2 = 0; r2 < 16; ++r2) {
                        float acc2 = 0.f;
#pragma unroll
                        for (int t = 0; t < 16; ++t)
                            acc2 += __shfl(wbc[t], r2) * wbc[t];
                        cv[r2] -= acc2;
                    }
                }
            } else {
#pragma unroll
                for (int r2 = 0; r2 < 16; ++r2) cv[r2] = 0.f;
            }
#pragma unroll
            for (int t = 0; t < 16; ++t) {
                float lt[16];
#pragma unroll
                for (int r2 = 0; r2 < 16; ++r2) lt[r2] = __shfl(cv[r2], t);
                float invs = 1.f / sqrtf(lt[t]);
                if (c == t) {
#pragma unroll
                    for (int r2 = 0; r2 < 16; ++r2) cv[r2] = (r2 >= t) ? lt[r2] * invs : 0.f;
                } else if (c > t && c < 16) {
                    float lc = lt[c] * invs;
#pragma unroll
                    for (int r2 = 0; r2 < 16; ++r2)
                        if (r2 > t) cv[r2] -= (lt[r2] * invs) * lc;
                }
            }
            float x[16], acb[16];
#pragma unroll
            for (int r2 = 0; r2 < 16; ++r2) acb[r2] = 0.f;
#pragma unroll
            for (int r2 = 0; r2 < 16; ++r2) {
                float Lrr = __shfl(cv[r2], r2);
                float xr = (((c == r2) ? 1.f : 0.f) - acb[r2]) / Lrr;
                x[r2] = xr;
#pragma unroll
                for (int q = r2 + 1; q < 16; ++q) acb[q] += __shfl(cv[q], r2) * xr;
            }
            if (c < 16) {
#pragma unroll
                for (int r2 = 0; r2 < 16; ++r2)
                    Amat[(base + c) * PITCH + base + r2] = x[r2];   // T^T into diag block
            }
        } else if (p > 0) {
            const int pb = base - 16;
            int t = tid - 64;                    // 0..191
            if (t < 128 - base) {                // z trailing update, rows base..127
                int i = base + t;
                const float* Lr = &Amat[i * PITCH + pb];
                float dv = 0.f, dd2 = 0.f;
#pragma unroll
                for (int t2 = 0; t2 < 16; ++t2) {
                    float lvv = Lr[t2];
                    dv  += lvv * zv[pb + t2];
                    dd2 += lvv * zd[pb + t2];
                }
                zv[i] -= dv; zd[i] -= dd2;
            }
            // U_col-below: rows base+16..127, cols base..base+15
            for (int idx = t; idx < R * 16; idx += 192) {
                int r2 = idx >> 4, jc = idx & 15;
                int i = base + 16 + r2, j = base + jc;
                const float* wi = &Wb[i];
                const float* wj = &Wb[j];
                float acc2 = 0.f;
#pragma unroll
                for (int t2 = 0; t2 < 16; ++t2)
                    acc2 += wi[t2 * PITCH] * wj[t2 * PITCH];
                Amat[i * PITCH + j] -= acc2;
            }
            // U_rest: lower 8x8 tiles, rows/cols >= base+16
            if (R > 0) {
                int nt = R >> 3;
                int ntri = (nt * (nt + 1)) >> 1;
                for (int tau = t; tau < ntri; tau += 192) {
                    float ft = sqrtf(8.f * (float)tau + 1.f);
                    int tr = (int)((ft - 1.f) * 0.5f);
                    while (((tr + 1) * (tr + 2)) / 2 <= tau) ++tr;
                    while ((tr * (tr + 1)) / 2 > tau) --tr;
                    int tc = tau - ((tr * (tr + 1)) >> 1);
                    int ii = base + 16 + tr * 8, jj = base + 16 + tc * 8;
                    float a2[8][8];
#pragma unroll
                    for (int r2 = 0; r2 < 8; ++r2)
#pragma unroll
                        for (int c2 = 0; c2 < 8; ++c2) a2[r2][c2] = 0.f;
#pragma unroll
                    for (int t2 = 0; t2 < 16; ++t2) {
                        const float* wr = &Wb[t2 * PITCH];
                        float4 x0 = *(const float4*)&wr[ii];
                        float4 x1 = *(const float4*)&wr[ii + 4];
                        float4 y0 = *(const float4*)&wr[jj];
                        float4 y1 = *(const float4*)&wr[jj + 4];
                        float xa[8] = {x0.x,x0.y,x0.z,x0.w, x1.x,x1.y,x1.z,x1.w};
                        float yb[8] = {y0.x,y0.y,y0.z,y0.w, y1.x,y1.y,y1.z,y1.w};
#pragma unroll
                        for (int r2 = 0; r2 < 8; ++r2)
#pragma unroll
                            for (int c2 = 0; c2 < 8; ++c2) a2[r2][c2] += xa[r2] * yb[c2];
                    }
#pragma unroll
                    for (int r2 = 0; r2 < 8; ++r2) {
                        float* Ar2 = &Amat[(ii + r2) * PITCH + jj];
                        float4 u0 = *(float4*)&Ar2[0];
                        float4 u1 = *(float4*)&Ar2[4];
                        u0.x -= a2[r2][0]; u0.y -= a2[r2][1]; u0.z -= a2[r2][2]; u0.w -= a2[r2][3];
                        u1.x -= a2[r2][4]; u1.y -= a2[r2][5]; u1.z -= a2[r2][6]; u1.w -= a2[r2][7];
                        *(float4*)&Ar2[0] = u0;
                        *(float4*)&Ar2[4] = u1;
                    }
                }
            }
        }
        __syncthreads();                         // T ready; updates applied
        if (R > 0 && tid < R) {
            int i = base + 16 + tid;
            const float* Ar = &Amat[i * PITCH + base];
            float4 q0 = *(const float4*)&Ar[0];
            float4 q1 = *(const float4*)&Ar[4];
            float4 q2 = *(const float4*)&Ar[8];
            float4 q3 = *(const float4*)&Ar[12];
            float rA[16] = {q0.x,q0.y,q0.z,q0.w, q1.x,q1.y,q1.z,q1.w,
                            q2.x,q2.y,q2.z,q2.w, q3.x,q3.y,q3.z,q3.w};
            float lo[16];
#pragma unroll
            for (int t = 0; t < 16; ++t) lo[t] = 0.f;
#pragma unroll
            for (int a = 0; a < 16; ++a) {
                float va = rA[a];
                const float* Trow = &Amat[(base + a) * PITCH + base];
                float4 t0 = *(const float4*)&Trow[0];
                float4 t1 = *(const float4*)&Trow[4];
                float4 t2 = *(const float4*)&Trow[8];
                float4 t3 = *(const float4*)&Trow[12];
                lo[0] += va * t0.x; lo[1] += va * t0.y; lo[2] += va * t0.z; lo[3] += va * t0.w;
                lo[4] += va * t1.x; lo[5] += va * t1.y; lo[6] += va * t1.z; lo[7] += va * t1.w;
                lo[8] += va * t2.x; lo[9] += va * t2.y; lo[10] += va * t2.z; lo[11] += va * t2.w;
                lo[12] += va * t3.x; lo[13] += va * t3.y; lo[14] += va * t3.z; lo[15] += va * t3.w;
            }
            float* Aw = &Amat[i * PITCH + base];
            *(float4*)&Aw[0]  = make_float4(lo[0], lo[1], lo[2], lo[3]);
            *(float4*)&Aw[4]  = make_float4(lo[4], lo[5], lo[6], lo[7]);
            *(float4*)&Aw[8]  = make_float4(lo[8], lo[9], lo[10], lo[11]);
            *(float4*)&Aw[12] = make_float4(lo[12], lo[13], lo[14], lo[15]);
#pragma unroll
            for (int t = 0; t < 16; ++t) Wb[t * PITCH + i] = lo[t];
        }
        if (tid >= 128 && tid < 160) {           // z' = T * z_panel (wave 2, lockstep)
            int t2 = (tid - 128) & 15;
            float* zp = (tid < 144) ? zv : zd;
            float a0 = 0.f;
#pragma unroll
            for (int a = 0; a < 16; ++a)
                a0 += Amat[(base + a) * PITCH + base + t2] * zp[base + a];
            zp[base + t2] = a0;
        }
    }
    // ---- phase 3b: X = L^{-1} via RECURSIVE DOUBLING (16 -> 32 -> 64 -> 128).
    __syncthreads();
    // Level 1: pairs q=0..3
    for (int t = tid; t < 128; t += 256) {   // step A: Yt = (L21*T1)^T
        int q = t >> 5, tt = t & 31;
        int c0 = (tt >> 2) * 2, r0 = (tt & 3) * 4;
        int rb = 32 * q + 16, cb = 32 * q;
        float a4[2][4] = {{0,0,0,0},{0,0,0,0}};
        for (int k = 0; k < 16; k += 4) {
            float4 xc0 = *(const float4*)&Amat[(cb + c0) * PITCH + cb + k];
            float4 xc1 = *(const float4*)&Amat[(cb + c0 + 1) * PITCH + cb + k];
#pragma unroll
            for (int rr = 0; rr < 4; ++rr) {
                float4 lr = *(const float4*)&Amat[(rb + r0 + rr) * PITCH + cb + k];
                a4[0][rr] += xc0.x * lr.x + xc0.y * lr.y + xc0.z * lr.z + xc0.w * lr.w;
                a4[1][rr] += xc1.x * lr.x + xc1.y * lr.y + xc1.z * lr.z + xc1.w * lr.w;
            }
        }
#pragma unroll
        for (int cc = 0; cc < 2; ++cc)
#pragma unroll
            for (int rr = 0; rr < 4; ++rr)
                Wb[q * 256 + (c0 + cc) * 16 + (r0 + rr)] = a4[cc][rr];
    }
    __syncthreads();
    for (int t = tid; t < 128; t += 256) {   // step B: X21^T = -(Yt * T2^T)
        int q = t >> 5, tt = t & 31;
        int c0 = (tt >> 2) * 2, r0 = (tt & 3) * 4;
        int rb = 32 * q + 16, cb = 32 * q;
        float a4[2][4] = {{0,0,0,0},{0,0,0,0}};
        for (int a = 0; a < 16; ++a) {
            float y0 = Wb[q * 256 + c0 * 16 + a];
            float y1 = Wb[q * 256 + (c0 + 1) * 16 + a];
            float4 t2 = *(const float4*)&Amat[(rb + a) * PITCH + rb + r0];
            a4[0][0] += y0 * t2.x; a4[0][1] += y0 * t2.y; a4[0][2] += y0 * t2.z; a4[0][3] += y0 * t2.w;
            a4[1][0] += y1 * t2.x; a4[1][1] += y1 * t2.y; a4[1][2] += y1 * t2.z; a4[1][3] += y1 * t2.w;
        }
#pragma unroll
        for (int cc = 0; cc < 2; ++cc)
#pragma unroll
            for (int rr = 0; rr < 4; ++rr)
                Amat[(cb + c0 + cc) * PITCH + rb + r0 + rr] = -a4[cc][rr];
    }
    __syncthreads();
    // Level 2: 32-super-pairs q=0..1
    {
        int q = tid >> 7, tt = tid & 127;
        int c0 = (tt >> 3) * 2, r0 = (tt & 7) * 4;
        int rb = 64 * q + 32, cb = 64 * q;
        int ks = c0 & ~15;
        float a4[2][4] = {{0,0,0,0},{0,0,0,0}};
        for (int k = ks; k < 32; k += 4) {
            float4 xc0 = *(const float4*)&Amat[(cb + c0) * PITCH + cb + k];
            float4 xc1 = *(const float4*)&Amat[(cb + c0 + 1) * PITCH + cb + k];
#pragma unroll
            for (int rr = 0; rr < 4; ++rr) {
                float4 lr = *(const float4*)&Amat[(rb + r0 + rr) * PITCH + cb + k];
                a4[0][rr] += xc0.x * lr.x + xc0.y * lr.y + xc0.z * lr.z + xc0.w * lr.w;
                a4[1][rr] += xc1.x * lr.x + xc1.y * lr.y + xc1.z * lr.z + xc1.w * lr.w;
            }
        }
#pragma unroll
        for (int cc = 0; cc < 2; ++cc)
#pragma unroll
            for (int rr = 0; rr < 4; ++rr)
                Wb[q * 1024 + (c0 + cc) * 32 + (r0 + rr)] = a4[cc][rr];
    }
    __syncthreads();
    {
        int q = tid >> 7, tt = tid & 127;
        int c0 = (tt >> 3) * 2, r0 = (tt & 7) * 4;
        int rb = 64 * q + 32, cb = 64 * q;
        int atop = (r0 & ~15) + 15;
        float a4[2][4] = {{0,0,0,0},{0,0,0,0}};
        for (int a = 0; a <= atop; ++a) {
            float y0 = Wb[q * 1024 + c0 * 32 + a];
            float y1 = Wb[q * 1024 + (c0 + 1) * 32 + a];
            float4 t2 = *(const float4*)&Amat[(rb + a) * PITCH + rb + r0];
            a4[0][0] += y0 * t2.x; a4[0][1] += y0 * t2.y; a4[0][2] += y0 * t2.z; a4[0][3] += y0 * t2.w;
            a4[1][0] += y1 * t2.x; a4[1][1] += y1 * t2.y; a4[1][2] += y1 * t2.z; a4[1][3] += y1 * t2.w;
        }
#pragma unroll
        for (int cc = 0; cc < 2; ++cc)
#pragma unroll
            for (int rr = 0; rr < 4; ++rr)
                Amat[(cb + c0 + cc) * PITCH + rb + r0 + rr] = -a4[cc][rr];
    }
    __syncthreads();
    // Level 3: 64-pair, two column halves
#pragma unroll
    for (int h3 = 0; h3 < 2; ++h3) {
        const int ch = 32 * h3;
        {
            int c0 = (tid >> 4) * 2, r0 = (tid & 15) * 4;
            int ks = (ch + c0) & ~15;
            float a4[2][4] = {{0,0,0,0},{0,0,0,0}};
            for (int k = ks; k < 64; k += 4) {
                float4 xc0 = *(const float4*)&Amat[(ch + c0) * PITCH + k];
                float4 xc1 = *(const float4*)&Amat[(ch + c0 + 1) * PITCH + k];
#pragma unroll
                for (int rr = 0; rr < 4; ++rr) {
                    float4 lr = *(const float4*)&Amat[(64 + r0 + rr) * PITCH + k];
                    a4[0][rr] += xc0.x * lr.x + xc0.y * lr.y + xc0.z * lr.z + xc0.w * lr.w;
                    a4[1][rr] += xc1.x * lr.x + xc1.y * lr.y + xc1.z * lr.z + xc1.w * lr.w;
                }
            }
#pragma unroll
            for (int cc = 0; cc < 2; ++cc)
#pragma unroll
                for (int rr = 0; rr < 4; ++rr)
                    Wb[(c0 + cc) * 64 + r0 + rr] = a4[cc][rr];
        }
        __syncthreads();
        {
            int c0 = (tid >> 4) * 2, r0 = (tid & 15) * 4;
            int atop = (r0 & ~15) + 15;
            float a4[2][4] = {{0,0,0,0},{0,0,0,0}};
            for (int a = 0; a <= atop; ++a) {
                float y0 = Wb[c0 * 64 + a];
                float y1 = Wb[(c0 + 1) * 64 + a];
                float4 t2 = *(const float4*)&Amat[(64 + a) * PITCH + 64 + r0];
                a4[0][0] += y0 * t2.x; a4[0][1] += y0 * t2.y; a4[0][2] += y0 * t2.z; a4[0][3] += y0 * t2.w;
                a4[1][0] += y1 * t2.x; a4[1][1] += y1 * t2.y; a4[1][2] += y1 * t2.z; a4[1][3] += y1 * t2.w;
            }
#pragma unroll
            for (int cc = 0; cc < 2; ++cc)
#pragma unroll
                for (int rr = 0; rr < 4; ++rr)
                    Amat[(ch + c0 + cc) * PITCH + 64 + r0 + rr] = -a4[cc][rr];
        }
        __syncthreads();
    }
    // ---- phase 4: trinv, qv, qd (one batched reduction)
    float v3[3] = {0.f, 0.f, 0.f};
    {
        int i = tid & 127, h = tid >> 7;
        int c0 = (i >> 4) << 4;
        int half = (128 - c0) >> 1;
        const float* Ar = &Amat[i * PITCH + c0 + h * half];
        for (int k2 = 0; k2 < half; k2 += 4) {
            float4 a = *(const float4*)&Ar[k2];
            v3[0] += a.x * a.x + a.y * a.y + a.z * a.z + a.w * a.w;
        }
    }
    if (tid < 128) {
        float a = zv[tid];  v3[1] = a * a;
        float d22 = zd[tid]; v3[2] = d22 * d22;
    }
    bsumN<3>(v3, red);
    if (tid == 0) {
        float n = 1.f + nv;
        float Aterm = trP - vsv / n;              // tr(Sq^{-1} Sp)
        float Bt = v3[0] + v3[1];                 // tr(Sp^{-1} Sq)
        float mq = dds - vds * vds / n;           // delta^T Sq^{-1} delta
        out[bid] = 0.25f * (Aterm + Bt - 256.f + mq + v3[2]);
    }
}

// ---------------------------------------------------------------- launch
extern "C" void kernel_launch(void* const* d_in, const int* in_sizes, int n_in,
                              void* d_out, int out_size, void* d_ws, size_t ws_size,
                              hipStream_t stream) {
    const float* wfm = (const float*)d_in[0];
    const float* wfd = (const float*)d_in[1];
    const float* sfm = (const float*)d_in[2];
    const float* sfd = (const float*)d_in[3];
    const float* W1 = (const float*)d_in[4];
    const float* B1 = (const float*)d_in[5];
    const float* W2 = (const float*)d_in[6];
    const float* B2 = (const float*)d_in[7];
    const float* W3 = (const float*)d_in[8];
    const float* B3 = (const float*)d_in[9];
    const float* W4 = (const float*)d_in[10];
    const float* B4 = (const float*)d_in[11];
    const float* lm = (const float*)d_in[12];
    const float* ldv = (const float*)d_in[13];
    float* out = (float*)d_out;
    float* ws = (float*)d_ws;

    float* wm = ws;                           // 262144
    float* wv = ws + 262144;                  // 262144
    float* sm = ws + 524288;                  // 1024
    float* sv = ws + 525312;                  // 1024
    float4* labscg = (float4*)(ws + 526336);  // 64 float4
    unsigned short* wvTg = (unsigned short*)(ws + 731392);  // 262144 bf16

    constexpr int SH_FLOATS = 19800;
    constexpr size_t SH_BYTES = SH_FLOATS * sizeof(float);   // 79200 B -> 2 blocks/CU
    (void)hipFuncSetAttribute((const void*)k4_fused,
                              hipFuncAttributeMaxDynamicSharedMemorySize,
                              (int)SH_BYTES);

    k1_gemm<<<dim3(258, 2), 256, 0, stream>>>(wfm, wfd, sfm, sfd,
                                              W1, B1, W2, B2, W3, B3, W4, B4,
                                              lm, ldv, wm, wv, sm, sv, labscg, wvTg);
    k4_fused<<<512, 256, SH_BYTES, stream>>>(wm, wv, wvTg, sm, sv, lm, ldv, labscg, out);
}

// Round 15
// 173.415 us; speedup vs baseline: 1.2661x; 1.0005x over previous
//
#include <hip/hip_runtime.h>
#include <hip/hip_bf16.h>

// B=8 S=256 H=768 D=128 L=64, all inputs f32.
// Outputs: relate_score (8*64) | lm_b (8*64*128) | lc_b (8*64*128*128), f32.

#define PITCH 132

typedef __attribute__((ext_vector_type(8))) short bf16x8;
typedef __attribute__((ext_vector_type(4))) float f32x4;

__device__ __forceinline__ float bf2f(unsigned int u) {
    union { unsigned int i; float f; } c; c.i = u << 16; return c.f;
}
__device__ __forceinline__ unsigned short f2bf(float f) {
    __hip_bfloat16 h = __float2bfloat16(f);
    union { __hip_bfloat16 h; unsigned short u; } c; c.h = h; return c.u;
}

// ---------------------------------------------------------------- K1: wm/wv GEMM (+ bf16 wv^T) + sm/sv (x==256) + label scalars (x==257)
__global__ __launch_bounds__(256, 2)
void k1_gemm(const float* __restrict__ Am, const float* __restrict__ Av,
             const float* __restrict__ sfm, const float* __restrict__ sfd,
             const float* __restrict__ W1, const float* __restrict__ B1,
             const float* __restrict__ W2, const float* __restrict__ B2,
             const float* __restrict__ W3, const float* __restrict__ B3,
             const float* __restrict__ W4, const float* __restrict__ B4,
             const float* __restrict__ lm, const float* __restrict__ ldv,
             float* __restrict__ wm, float* __restrict__ wv,
             float* __restrict__ sm, float* __restrict__ sv,
             float4* __restrict__ labscg,
             unsigned short* __restrict__ wvTg) {
    const int tid = threadIdx.x;
    const int sel = blockIdx.y;
    if (blockIdx.x == 257) {           // label scalars: mmp, |v|^2, vmp per label
        if (sel == 0) {
            int l = tid >> 2, q = tid & 3;
            const float* mr = lm + (size_t)l * 128 + q * 32;
            const float* vr = ldv + (size_t)l * 128 + q * 32;
            float s0 = 0.f, s1 = 0.f, s2 = 0.f;
            for (int k = 0; k < 32; k += 4) {
                float4 m = *(const float4*)&mr[k];
                float4 v = *(const float4*)&vr[k];
                s0 += m.x * m.x + m.y * m.y + m.z * m.z + m.w * m.w;
                s1 += v.x * v.x + v.y * v.y + v.z * v.z + v.w * v.w;
                s2 += m.x * v.x + m.y * v.y + m.z * v.z + m.w * v.w;
            }
            s0 += __shfl_xor(s0, 1); s0 += __shfl_xor(s0, 2);
            s1 += __shfl_xor(s1, 1); s1 += __shfl_xor(s1, 2);
            s2 += __shfl_xor(s2, 1); s2 += __shfl_xor(s2, 2);
            if (q == 0) labscg[l] = make_float4(s0, s1, s2, 0.f);
        }
        return;
    }
    __shared__ float At[8][64];
    __shared__ __align__(16) float Wt[64][128];
    __shared__ float tileT[8][129];
    const bool sentB = (blockIdx.x == 256);
    const float* A  = sentB ? (sel ? sfd : sfm) : (sel ? Av : Am);
    const float* W  = sentB ? (sel ? W4 : W3) : (sel ? W2 : W1);
    const float* Bs = sentB ? (sel ? B4 : B3) : (sel ? B2 : B1);
    float* D = sentB ? (sel ? sv : sm) : (sel ? wv : wm);
    const int R0 = sentB ? 0 : blockIdx.x * 8;
    const int r = tid >> 5;
    const int j0 = (tid & 31) * 4;
    float acc[4] = {0.f, 0.f, 0.f, 0.f};
    for (int k0 = 0; k0 < 768; k0 += 64) {
        __syncthreads();
        {
            int f = tid;
            At[f >> 6][f & 63] = A[(size_t)(R0 + (f >> 6)) * 768 + k0 + (f & 63)];
            f = tid + 256;
            At[f >> 6][f & 63] = A[(size_t)(R0 + (f >> 6)) * 768 + k0 + (f & 63)];
        }
#pragma unroll
        for (int it = 0; it < 8; ++it) {
            int f = tid + it * 256;
            int rr = f >> 5, c4 = (f & 31) * 4;
            *(float4*)&Wt[rr][c4] = *(const float4*)&W[(size_t)(k0 + rr) * 128 + c4];
        }
        __syncthreads();
#pragma unroll 16
        for (int kk = 0; kk < 64; ++kk) {
            float a = At[r][kk];
            float4 w0 = *(const float4*)&Wt[kk][j0];
            acc[0] += a * w0.x; acc[1] += a * w0.y; acc[2] += a * w0.z; acc[3] += a * w0.w;
        }
    }
    {
        float b0 = Bs[j0], b1 = Bs[j0 + 1], b2 = Bs[j0 + 2], b3 = Bs[j0 + 3];
        float4 o = make_float4(acc[0] + b0, acc[1] + b1, acc[2] + b2, acc[3] + b3);
        *(float4*)&D[(size_t)(R0 + r) * 128 + j0] = o;
        tileT[r][j0 + 0] = o.x; tileT[r][j0 + 1] = o.y;
        tileT[r][j0 + 2] = o.z; tileT[r][j0 + 3] = o.w;
    }
    if (sel && !sentB) {
        __syncthreads();
        if (tid < 128) {
            int d = tid;
            unsigned short u[8];
#pragma unroll
            for (int ss = 0; ss < 8; ++ss) u[ss] = f2bf(tileT[ss][d]);
            unsigned int p0 = (unsigned int)u[0] | ((unsigned int)u[1] << 16);
            unsigned int p1 = (unsigned int)u[2] | ((unsigned int)u[3] << 16);
            unsigned int p2 = (unsigned int)u[4] | ((unsigned int)u[5] << 16);
            unsigned int p3 = (unsigned int)u[6] | ((unsigned int)u[7] << 16);
            unsigned short* dst = wvTg + (size_t)(R0 >> 8) * 32768 + (size_t)d * 256 + (R0 & 255);
            *(uint4*)dst = make_uint4(p0, p1, p2, p3);
        }
    }
}

// ---------------------------------------------------------------- batched block reduce (4 waves), one barrier set
template <int N>
__device__ __forceinline__ void bsumN(float* v, float* red) {
#pragma unroll
    for (int o = 32; o; o >>= 1)
#pragma unroll
        for (int n = 0; n < N; ++n) v[n] += __shfl_xor(v[n], o);
    __syncthreads();
    if ((threadIdx.x & 63) == 0) {
        int w = threadIdx.x >> 6;
#pragma unroll
        for (int n = 0; n < N; ++n) red[w * N + n] = v[n];
    }
    __syncthreads();
#pragma unroll
    for (int n = 0; n < N; ++n)
        v[n] = red[0 * N + n] + red[1 * N + n] + red[2 * N + n] + red[3 * N + n];
    __syncthreads();
}

// ---------------------------------------------------------------- K4: fused; 2-barrier lookahead Cholesky + recursive-doubling inverse.
__global__ __launch_bounds__(256, 2)
void k4_fused(const float* __restrict__ wm, const float* __restrict__ wv,
              const unsigned short* __restrict__ wvTg,
              const float* __restrict__ smg, const float* __restrict__ svg,
              const float* __restrict__ lmg, const float* __restrict__ ldvg,
              const float4* __restrict__ labscg,
              float* __restrict__ out) {
    extern __shared__ float smem[];
    float* Amat = smem;                 // 16896 f32
    float* Wb   = smem + 16896;         // 2112 (RD temp alias)
    float* ssq  = smem + 19008;         // 256
    float* svr  = smem + 19264;         // 128
    float* vrow = smem + 19392;         // 128
    float* zv   = smem + 19520;         // 128  (mu until delta built)
    float* zd   = smem + 19648;         // 128
    float* red  = smem + 19776;         // 24
    float* scoreL = Amat;               // 256 (pre-staging only)
    float* vpart  = Amat + 256;         // 1024 (pre-staging only)

    const int tid = threadIdx.x;
    const int bid = blockIdx.x;
    const int b = bid >> 6, l = bid & 63;

    if (tid < 128) {
        svr[tid]  = svg[b * 128 + tid];
        vrow[tid] = ldvg[l * 128 + tid];
        zv[tid]   = lmg[l * 128 + tid];     // mu (temporary)
    }
    __syncthreads();
    // ---- early output writes: lm_b[b][l], lc_b[b][l]
    if (tid < 32) {
        float4 v = *(const float4*)&lmg[l * 128 + tid * 4];
        *(float4*)&out[512 + (size_t)bid * 128 + tid * 4] = v;
    }
    {
        float* lcb = out + 512 + 65536 + (size_t)bid * 16384;
#pragma unroll
        for (int q = 0; q < 16; ++q) {
            int flat4 = q * 256 + tid;
            int i = flat4 >> 5;
            int j4 = (flat4 & 31) * 4;
            float vi = vrow[i];
            float4 r;
            r.x = vi * vrow[j4 + 0] + ((i == j4 + 0) ? 1.f : 0.f);
            r.y = vi * vrow[j4 + 1] + ((i == j4 + 1) ? 1.f : 0.f);
            r.z = vi * vrow[j4 + 2] + ((i == j4 + 2) ? 1.f : 0.f);
            r.w = vi * vrow[j4 + 3] + ((i == j4 + 3) ? 1.f : 0.f);
            *(float4*)&lcb[(size_t)flat4 * 4] = r;
        }
    }
    // ---- phase 0a: label scalars (precomputed in k1)
    float4 lsv = labscg[l];
    const float mmp = lsv.x, np = 1.f + lsv.y, vmp = lsv.z;
    // ---- phase 0b: per-row dots + row scalars (thread = s)
    const float4* wmr = (const float4*)(wm + (size_t)(b * 256 + tid) * 128);
    const float4* wvr = (const float4*)(wv + (size_t)(b * 256 + tid) * 128);
    float md = 0.f, dot = 0.f, pvv = 0.f, vq = 0.f;
    float smm = 0.f, svv = 0.f, smv = 0.f;
#pragma unroll 8
    for (int q = 0; q < 32; ++q) {
        float4 xm = wmr[q], xv = wvr[q];
        const float* m4 = &zv[q * 4];
        const float* v4 = &vrow[q * 4];
        md  += m4[0] * xm.x + m4[1] * xm.y + m4[2] * xm.z + m4[3] * xm.w;
        dot += v4[0] * xv.x + v4[1] * xv.y + v4[2] * xv.z + v4[3] * xv.w;
        pvv += m4[0] * xv.x + m4[1] * xv.y + m4[2] * xv.z + m4[3] * xv.w;
        vq  += v4[0] * xm.x + v4[1] * xm.y + v4[2] * xm.z + v4[3] * xm.w;
        smm += xm.x * xm.x + xm.y * xm.y + xm.z * xm.z + xm.w * xm.w;
        svv += xv.x * xv.x + xv.y * xv.y + xv.z * xv.z + xv.w * xv.w;
        smv += xm.x * xv.x + xm.y * xv.y + xm.z * xv.z + xm.w * xv.w;
    }
    float nq = 1.f + svv;
    float d2 = smm - 2.f * md + mmp;
    float vqd = smv - pvv, vpd = vq - vmp;
    float inq = 1.f / nq, inp = 1.f / np;
    float maha_q = d2 - vqd * vqd * inq;
    float maha_p = d2 - vpd * vpd * inp;
    float logit = 0.25f * ((np - 1.f) + (nq - 1.f)
                           - (nq - 1.f + dot * dot) * inq
                           - (np - 1.f + dot * dot) * inp
                           + maha_q + maha_p);
    // ---- phase 0c: softmax over 256 threads (2 barriers: distinct red slots)
    float mx = logit;
#pragma unroll
    for (int o = 32; o; o >>= 1) mx = fmaxf(mx, __shfl_xor(mx, o));
    if ((tid & 63) == 0) red[tid >> 6] = mx;
    __syncthreads();
    mx = fmaxf(fmaxf(red[0], red[1]), fmaxf(red[2], red[3]));
    float e = expf(logit - mx);
    float s = e;
#pragma unroll
    for (int o = 32; o; o >>= 1) s += __shfl_xor(s, o);
    if ((tid & 63) == 0) red[8 + (tid >> 6)] = s;
    __syncthreads();
    float tot = red[8] + red[9] + red[10] + red[11];
    float sc = e / tot;
    scoreL[tid] = sc;
    ssq[tid] = sqrtf(sc);
    __syncthreads();
    // ---- phase 0d: v_mean = score @ wm
    {
        int d4 = (tid & 31) * 4, sg = tid >> 5;
        const float* wmb = wm + (size_t)b * 256 * 128;
        float ax = 0.f, ay = 0.f, az = 0.f, aw = 0.f;
        for (int s2 = sg * 32; s2 < sg * 32 + 32; ++s2) {
            float w = scoreL[s2];
            float4 x = *(const float4*)&wmb[(size_t)s2 * 128 + d4];
            ax += w * x.x; ay += w * x.y; az += w * x.z; aw += w * x.w;
        }
        *(float4*)&vpart[sg * 128 + d4] = make_float4(ax, ay, az, aw);
    }
    __syncthreads();
    if (tid < 128) {
        float vm8 = 0.f;
#pragma unroll
        for (int g2 = 0; g2 < 8; ++g2) vm8 += vpart[g2 * 128 + tid];
        zd[tid] = zv[tid] - 0.5f * (smg[b * 128 + tid] + vm8);  // delta
        zv[tid] = vrow[tid];                                     // rhs v
    }
    __syncthreads();
    // ---- phase 1a: stage S^T (bf16, rows d, 264-bf16 pitch), scaled by sqrt(score)
    {
        unsigned short* Sb = (unsigned short*)Amat;
        const unsigned short* src = wvTg + (size_t)b * 32768;
        const int s0 = (tid & 31) * 8;
        float ssv[8];
#pragma unroll
        for (int j = 0; j < 8; ++j) ssv[j] = ssq[s0 + j];
#pragma unroll
        for (int it = 0; it < 16; ++it) {
            int f8 = tid + it * 256;
            int d = f8 >> 5;
            uint4 raw = *(const uint4*)&src[(size_t)f8 * 8];
            unsigned int p0 = (unsigned int)f2bf(bf2f(raw.x & 0xffffu) * ssv[0])
                            | ((unsigned int)f2bf(bf2f(raw.x >> 16) * ssv[1]) << 16);
            unsigned int p1 = (unsigned int)f2bf(bf2f(raw.y & 0xffffu) * ssv[2])
                            | ((unsigned int)f2bf(bf2f(raw.y >> 16) * ssv[3]) << 16);
            unsigned int p2 = (unsigned int)f2bf(bf2f(raw.z & 0xffffu) * ssv[4])
                            | ((unsigned int)f2bf(bf2f(raw.z >> 16) * ssv[5]) << 16);
            unsigned int p3 = (unsigned int)f2bf(bf2f(raw.w & 0xffffu) * ssv[6])
                            | ((unsigned int)f2bf(bf2f(raw.w >> 16) * ssv[7]) << 16);
            *(uint4*)&Sb[(size_t)d * 264 + s0] = make_uint4(p0, p1, p2, p3);
        }
    }
    __syncthreads();
    // ---- phase 1b: M = S^T S via MFMA; wave w computes tile-rows w and w+4
    {
        const unsigned short* Sb = (const unsigned short*)Amat;
        const int w = tid >> 6, ln = tid & 63;
        const int rl = ln & 15, g = ln >> 4;
        const int arow0 = 16 * w + rl;
        const int arow1 = 16 * (w + 4) + rl;
        f32x4 acc0[8], acc1[8];
#pragma unroll
        for (int t = 0; t < 8; ++t) {
            acc0[t] = (f32x4){0.f, 0.f, 0.f, 0.f};
            acc1[t] = (f32x4){0.f, 0.f, 0.f, 0.f};
        }
#pragma unroll
        for (int ks = 0; ks < 8; ++ks) {
            bf16x8 a0 = *(const bf16x8*)&Sb[(size_t)arow0 * 264 + ks * 32 + g * 8];
            bf16x8 a1 = *(const bf16x8*)&Sb[(size_t)arow1 * 264 + ks * 32 + g * 8];
#pragma unroll
            for (int tj = 0; tj < 8; ++tj) {
                bf16x8 bb = *(const bf16x8*)&Sb[(size_t)(16 * tj + rl) * 264 + ks * 32 + g * 8];
                acc0[tj] = __builtin_amdgcn_mfma_f32_16x16x32_bf16(a0, bb, acc0[tj], 0, 0, 0);
                acc1[tj] = __builtin_amdgcn_mfma_f32_16x16x32_bf16(a1, bb, acc1[tj], 0, 0, 0);
            }
        }
        __syncthreads();
#pragma unroll
        for (int tj = 0; tj < 8; ++tj) {
            int j = 16 * tj + rl;
            float svj = svr[j];
#pragma unroll
            for (int r = 0; r < 4; ++r) {
                int i = 16 * w + g * 4 + r;
                Amat[i * PITCH + j] = ((i == j) ? 1.f : 0.f) + 0.5f * (svr[i] * svj + acc0[tj][r]);
                int i2 = 16 * (w + 4) + g * 4 + r;
                Amat[i2 * PITCH + j] = ((i2 == j) ? 1.f : 0.f) + 0.5f * (svr[i2] * svj + acc1[tj][r]);
            }
        }
    }
    __syncthreads();
    // ---- phase 2c: label-side closed-form terms, one batched reduction
    float v5[5] = {0.f, 0.f, 0.f, 0.f, 0.f};
    if (tid < 128) {
        v5[0] = Amat[tid * PITCH + tid];
        float vv = vrow[tid], de = zd[tid];
        v5[1] = vv * vv; v5[2] = de * de; v5[3] = vv * de;
    }
    {
        int i = tid >> 1, h = tid & 1;
        const float* Ar = &Amat[i * PITCH + h * 64];
        const float* vr = &vrow[h * 64];
        float s2 = 0.f;
        for (int k2 = 0; k2 < 64; k2 += 4) {
            float4 a = *(const float4*)&Ar[k2];
            s2 += a.x * vr[k2] + a.y * vr[k2 + 1] + a.z * vr[k2 + 2] + a.w * vr[k2 + 3];
        }
        v5[4] = vrow[i] * s2;
    }
    bsumN<5>(v5, red);
    const float trP = v5[0], nv = v5[1], dds = v5[2], vds = v5[3], vsv = v5[4];
    // ---- phase 3: blocked Cholesky, 2 barriers/panel.
    for (int p = 0; p < 8; ++p) {
        const int base = 16 * p;
        const int R = 112 - base;
        __syncthreads();                         // solve(p-1)/Wb(p-1)/z'(p-1) visible
        if (tid < 64) {
            const int c = tid;
            float cv[16];
            if (c < 16) {
#pragma unroll
                for (int r2 = 0; r2 < 16; ++r2) {
                    int hi = (r2 >= c) ? r2 : c, lo2 = (r2 >= c) ? c : r2;
                    cv[r2] = Amat[(base + hi) * PITCH + base + lo2];
                }
                if (p > 0) {
                    float wbc[16];
#pragma unroll
                    for (int t = 0; t < 16; ++t) wbc[t] = Wb[t * PITCH + base + c];
#pragma unroll
                    for (int r2 = 0; r2 < 16; ++r2) {
                        float acc2 = 0.f;
#pragma unroll
                        for (int t = 0; t < 16; ++t)
                            acc2 += __shfl(wbc[t], r2) * wbc[t];
                        cv[r2] -= acc2;
                    }
                }
            } else {
#pragma unroll
                for (int r2 = 0; r2 < 16; ++r2) cv[r2] = 0.f;
            }
#pragma unroll
            for (int t = 0; t < 16; ++t) {
                float lt[16];
#pragma unroll
                for (int r2 = 0; r2 < 16; ++r2) lt[r2] = __shfl(cv[r2], t);
                float invs = 1.f / sqrtf(lt[t]);
                if (c == t) {
#pragma unroll
                    for (int r2 = 0; r2 < 16; ++r2) cv[r2] = (r2 >= t) ? lt[r2] * invs : 0.f;
                } else if (c > t && c < 16) {
                    float lc = lt[c] * invs;
#pragma unroll
                    for (int r2 = 0; r2 < 16; ++r2)
                        if (r2 > t) cv[r2] -= (lt[r2] * invs) * lc;
                }
            }
            float x[16], acb[16];
#pragma unroll
            for (int r2 = 0; r2 < 16; ++r2) acb[r2] = 0.f;
#pragma unroll
            for (int r2 = 0; r2 < 16; ++r2) {
                float Lrr = __shfl(cv[r2], r2);
                float xr = (((c == r2) ? 1.f : 0.f) - acb[r2]) / Lrr;
                x[r2] = xr;
#pragma unroll
                for (int q = r2 + 1; q < 16; ++q) acb[q] += __shfl(cv[q], r2) * xr;
            }
            if (c < 16) {
#pragma unroll
                for (int r2 = 0; r2 < 16; ++r2)
                    Amat[(base + c) * PITCH + base + r2] = x[r2];   // T^T into diag block
            }
        } else if (p > 0) {
            const int pb = base - 16;
            int t = tid - 64;                    // 0..191
            if (t < 128 - base) {                // z trailing update, rows base..127
                int i = base + t;
                const float* Lr = &Amat[i * PITCH + pb];
                float dv = 0.f, dd2 = 0.f;
#pragma unroll
                for (int t2 = 0; t2 < 16; ++t2) {
                    float lvv = Lr[t2];
                    dv  += lvv * zv[pb + t2];
                    dd2 += lvv * zd[pb + t2];
                }
                zv[i] -= dv; zd[i] -= dd2;
            }
            // U_col-below: rows base+16..127, cols base..base+15
            for (int idx = t; idx < R * 16; idx += 192) {
                int r2 = idx >> 4, jc = idx & 15;
                int i = base + 16 + r2, j = base + jc;
                const float* wi = &Wb[i];
                const float* wj = &Wb[j];
                float acc2 = 0.f;
#pragma unroll
                for (int t2 = 0; t2 < 16; ++t2)
                    acc2 += wi[t2 * PITCH] * wj[t2 * PITCH];
                Amat[i * PITCH + j] -= acc2;
            }
            // U_rest: lower 8x8 tiles, rows/cols >= base+16
            if (R > 0) {
                int nt = R >> 3;
                int ntri = (nt * (nt + 1)) >> 1;
                for (int tau = t; tau < ntri; tau += 192) {
                    float ft = sqrtf(8.f * (float)tau + 1.f);
                    int tr = (int)((ft - 1.f) * 0.5f);
                    while (((tr + 1) * (tr + 2)) / 2 <= tau) ++tr;
                    while ((tr * (tr + 1)) / 2 > tau) --tr;
                    int tc = tau - ((tr * (tr + 1)) >> 1);
                    int ii = base + 16 + tr * 8, jj = base + 16 + tc * 8;
                    float a2[8][8];
#pragma unroll
                    for (int r2 = 0; r2 < 8; ++r2)
#pragma unroll
                        for (int c2 = 0; c2 < 8; ++c2) a2[r2][c2] = 0.f;
#pragma unroll
                    for (int t2 = 0; t2 < 16; ++t2) {
                        const float* wr = &Wb[t2 * PITCH];
                        float4 x0 = *(const float4*)&wr[ii];
                        float4 x1 = *(const float4*)&wr[ii + 4];
                        float4 y0 = *(const float4*)&wr[jj];
                        float4 y1 = *(const float4*)&wr[jj + 4];
                        float xa[8] = {x0.x,x0.y,x0.z,x0.w, x1.x,x1.y,x1.z,x1.w};
                        float yb[8] = {y0.x,y0.y,y0.z,y0.w, y1.x,y1.y,y1.z,y1.w};
#pragma unroll
                        for (int r2 = 0; r2 < 8; ++r2)
#pragma unroll
                            for (int c2 = 0; c2 < 8; ++c2) a2[r2][c2] += xa[r2] * yb[c2];
                    }
#pragma unroll
                    for (int r2 = 0; r2 < 8; ++r2) {
                        float* Ar2 = &Amat[(ii + r2) * PITCH + jj];
                        float4 u0 = *(float4*)&Ar2[0];
                        float4 u1 = *(float4*)&Ar2[4];
                        u0.x -= a2[r2][0]; u0.y -= a2[r2][1]; u0.z -= a2[r2][2]; u0.w -= a2[r2][3];
                        u1.x -= a2[r2][4]; u1.y -= a2[r2][5]; u1.z -= a2[r2][6]; u1.w -= a2[r2][7];
                        *(float4*)&Ar2[0] = u0;
                        *(float4*)&Ar2[4] = u1;
                    }
                }
            }
        }
        __syncthreads();                         // T ready; updates applied
        if (R > 0 && tid < R) {
            int i = base + 16 + tid;
            const float* Ar = &Amat[i * PITCH + base];
            float4 q0 = *(const float4*)&Ar[0];
            float4 q1 = *(const float4*)&Ar[4];
            float4 q2 = *(const float4*)&Ar[8];
            float4 q3 = *(const float4*)&Ar[12];
            float rA[16] = {q0.x,q0.y,q0.z,q0.w, q1.x,q1.y,q1.z,q1.w,
                            q2.x,q2.y,q2.z,q2.w, q3.x,q3.y,q3.z,q3.w};
            float lo[16];
#pragma unroll
            for (int t = 0; t < 16; ++t) lo[t] = 0.f;
#pragma unroll
            for (int a = 0; a < 16; ++a) {
                float va = rA[a];
                const float* Trow = &Amat[(base + a) * PITCH + base];
                float4 t0 = *(const float4*)&Trow[0];
                float4 t1 = *(const float4*)&Trow[4];
                float4 t2 = *(const float4*)&Trow[8];
                float4 t3 = *(const float4*)&Trow[12];
                lo[0] += va * t0.x; lo[1] += va * t0.y; lo[2] += va * t0.z; lo[3] += va * t0.w;
                lo[4] += va * t1.x; lo[5] += va * t1.y; lo[6] += va * t1.z; lo[7] += va * t1.w;
                lo[8] += va * t2.x; lo[9] += va * t2.y; lo[10] += va * t2.z; lo[11] += va * t2.w;
                lo[12] += va * t3.x; lo[13] += va * t3.y; lo[14] += va * t3.z; lo[15] += va * t3.w;
            }
            float* Aw = &Amat[i * PITCH + base];
            *(float4*)&Aw[0]  = make_float4(lo[0], lo[1], lo[2], lo[3]);
            *(float4*)&Aw[4]  = make_float4(lo[4], lo[5], lo[6], lo[7]);
            *(float4*)&Aw[8]  = make_float4(lo[8], lo[9], lo[10], lo[11]);
            *(float4*)&Aw[12] = make_float4(lo[12], lo[13], lo[14], lo[15]);
#pragma unroll
            for (int t = 0; t < 16; ++t) Wb[t * PITCH + i] = lo[t];
        }
        if (tid >= 128 && tid < 160) {           // z' = T * z_panel (wave 2, lockstep)
            int t2 = (tid - 128) & 15;
            float* zp = (tid < 144) ? zv : zd;
            float a0 = 0.f;
#pragma unroll
            for (int a = 0; a < 16; ++a)
                a0 += Amat[(base + a) * PITCH + base + t2] * zp[base + a];
            zp[base + t2] = a0;
        }
    }
    // ---- phase 3b: X = L^{-1} via RECURSIVE DOUBLING (16 -> 32 -> 64 -> 128).
    __syncthreads();
    // Level 1: pairs q=0..3
    for (int t = tid; t < 128; t += 256) {   // step A: Yt = (L21*T1)^T
        int q = t >> 5, tt = t & 31;
        int c0 = (tt >> 2) * 2, r0 = (tt & 3) * 4;
        int rb = 32 * q + 16, cb = 32 * q;
        float a4[2][4] = {{0,0,0,0},{0,0,0,0}};
        for (int k = 0; k < 16; k += 4) {
            float4 xc0 = *(const float4*)&Amat[(cb + c0) * PITCH + cb + k];
            float4 xc1 = *(const float4*)&Amat[(cb + c0 + 1) * PITCH + cb + k];
#pragma unroll
            for (int rr = 0; rr < 4; ++rr) {
                float4 lr = *(const float4*)&Amat[(rb + r0 + rr) * PITCH + cb + k];
                a4[0][rr] += xc0.x * lr.x + xc0.y * lr.y + xc0.z * lr.z + xc0.w * lr.w;
                a4[1][rr] += xc1.x * lr.x + xc1.y * lr.y + xc1.z * lr.z + xc1.w * lr.w;
            }
        }
#pragma unroll
        for (int cc = 0; cc < 2; ++cc)
#pragma unroll
            for (int rr = 0; rr < 4; ++rr)
                Wb[q * 256 + (c0 + cc) * 16 + (r0 + rr)] = a4[cc][rr];
    }
    __syncthreads();
    for (int t = tid; t < 128; t += 256) {   // step B: X21^T = -(Yt * T2^T)
        int q = t >> 5, tt = t & 31;
        int c0 = (tt >> 2) * 2, r0 = (tt & 3) * 4;
        int rb = 32 * q + 16, cb = 32 * q;
        float a4[2][4] = {{0,0,0,0},{0,0,0,0}};
        for (int a = 0; a < 16; ++a) {
            float y0 = Wb[q * 256 + c0 * 16 + a];
            float y1 = Wb[q * 256 + (c0 + 1) * 16 + a];
            float4 t2 = *(const float4*)&Amat[(rb + a) * PITCH + rb + r0];
            a4[0][0] += y0 * t2.x; a4[0][1] += y0 * t2.y; a4[0][2] += y0 * t2.z; a4[0][3] += y0 * t2.w;
            a4[1][0] += y1 * t2.x; a4[1][1] += y1 * t2.y; a4[1][2] += y1 * t2.z; a4[1][3] += y1 * t2.w;
        }
#pragma unroll
        for (int cc = 0; cc < 2; ++cc)
#pragma unroll
            for (int rr = 0; rr < 4; ++rr)
                Amat[(cb + c0 + cc) * PITCH + rb + r0 + rr] = -a4[cc][rr];
    }
    __syncthreads();
    // Level 2: 32-super-pairs q=0..1
    {
        int q = tid >> 7, tt = tid & 127;
        int c0 = (tt >> 3) * 2, r0 = (tt & 7) * 4;
        int rb = 64 * q + 32, cb = 64 * q;
        int ks = c0 & ~15;
        float a4[2][4] = {{0,0,0,0},{0,0,0,0}};
        for (int k = ks; k < 32; k += 4) {
            float4 xc0 = *(const float4*)&Amat[(cb + c0) * PITCH + cb + k];
            float4 xc1 = *(const float4*)&Amat[(cb + c0 + 1) * PITCH + cb + k];
#pragma unroll
            for (int rr = 0; rr < 4; ++rr) {
                float4 lr = *(const float4*)&Amat[(rb + r0 + rr) * PITCH + cb + k];
                a4[0][rr] += xc0.x * lr.x + xc0.y * lr.y + xc0.z * lr.z + xc0.w * lr.w;
                a4[1][rr] += xc1.x * lr.x + xc1.y * lr.y + xc1.z * lr.z + xc1.w * lr.w;
            }
        }
#pragma unroll
        for (int cc = 0; cc < 2; ++cc)
#pragma unroll
            for (int rr = 0; rr < 4; ++rr)
                Wb[q * 1024 + (c0 + cc) * 32 + (r0 + rr)] = a4[cc][rr];
    }
    __syncthreads();
    {
        int q = tid >> 7, tt = tid & 127;
        int c0 = (tt >> 3) * 2, r0 = (tt & 7) * 4;
        int rb = 64 * q + 32, cb = 64 * q;
        int atop = (r0 & ~15) + 15;
        float a4[2][4] = {{0,0,0,0},{0,0,0,0}};
        for (int a = 0; a <= atop; ++a) {
            float y0 = Wb[q * 1024 + c0 * 32 + a];
            float y1 = Wb[q * 1024 + (c0 + 1) * 32 + a];
            float4 t2 = *(const float4*)&Amat[(rb + a) * PITCH + rb + r0];
            a4[0][0] += y0 * t2.x; a4[0][1] += y0 * t2.y; a4[0][2] += y0 * t2.z; a4[0][3] += y0 * t2.w;
            a4[1][0] += y1 * t2.x; a4[1][1] += y1 * t2.y; a4[1][2] += y1 * t2.z; a4[1][3] += y1 * t2.w;
        }
#pragma unroll
        for (int cc = 0; cc < 2; ++cc)
#pragma unroll
            for (int rr = 0; rr < 4; ++rr)
                Amat[(cb + c0 + cc) * PITCH + rb + r0 + rr] = -a4[cc][rr];
    }
    __syncthreads();
    // Level 3: 64-pair, two column halves
#pragma unroll
    for (int h3 = 0; h3 < 2; ++h3) {
        const int ch = 32 * h3;
        {
            int c0 = (tid >> 4) * 2, r0 = (tid & 15) * 4;
            int ks = (ch + c0) & ~15;
            float a4[2][4] = {{0,0,0,0},{0,0,0,0}};
            for (int k = ks; k < 64; k += 4) {
                float4 xc0 = *(const float4*)&Amat[(ch + c0) * PITCH + k];
                float4 xc1 = *(const float4*)&Amat[(ch + c0 + 1) * PITCH + k];
#pragma unroll
                for (int rr = 0; rr < 4; ++rr) {
                    float4 lr = *(const float4*)&Amat[(64 + r0 + rr) * PITCH + k];
                    a4[0][rr] += xc0.x * lr.x + xc0.y * lr.y + xc0.z * lr.z + xc0.w * lr.w;
                    a4[1][rr] += xc1.x * lr.x + xc1.y * lr.y + xc1.z * lr.z + xc1.w * lr.w;
                }
            }
#pragma unroll
            for (int cc = 0; cc < 2; ++cc)
#pragma unroll
                for (int rr = 0; rr < 4; ++rr)
                    Wb[(c0 + cc) * 64 + r0 + rr] = a4[cc][rr];
        }
        __syncthreads();
        {
            int c0 = (tid >> 4) * 2, r0 = (tid & 15) * 4;
            int atop = (r0 & ~15) + 15;
            float a4[2][4] = {{0,0,0,0},{0,0,0,0}};
            for (int a = 0; a <= atop; ++a) {
                float y0 = Wb[c0 * 64 + a];
                float y1 = Wb[(c0 + 1) * 64 + a];
                float4 t2 = *(const float4*)&Amat[(64 + a) * PITCH + 64 + r0];
                a4[0][0] += y0 * t2.x; a4[0][1] += y0 * t2.y; a4[0][2] += y0 * t2.z; a4[0][3] += y0 * t2.w;
                a4[1][0] += y1 * t2.x; a4[1][1] += y1 * t2.y; a4[1][2] += y1 * t2.z; a4[1][3] += y1 * t2.w;
            }
#pragma unroll
            for (int cc = 0; cc < 2; ++cc)
#pragma unroll
                for (int rr = 0; rr < 4; ++rr)
                    Amat[(ch + c0 + cc) * PITCH + 64 + r0 + rr] = -a4[cc][rr];
        }
        __syncthreads();
    }
    // ---- phase 4: trinv, qv, qd (one batched reduction)
    float v3[3] = {0.f, 0.f, 0.f};
    {
        int i = tid & 127, h = tid >> 7;
        int c0 = (i >> 4) << 4;
        int half = (128 - c0) >> 1;
        const float* Ar = &Amat[i * PITCH + c0 + h * half];
        for (int k2 = 0; k2 < half; k2 += 4) {
            float4 a = *(const float4*)&Ar[k2];
            v3[0] += a.x * a.x + a.y * a.y + a.z * a.z + a.w * a.w;
        }
    }
    if (tid < 128) {
        float a = zv[tid];  v3[1] = a * a;
        float d22 = zd[tid]; v3[2] = d22 * d22;
    }
    bsumN<3>(v3, red);
    if (tid == 0) {
        float n = 1.f + nv;
        float Aterm = trP - vsv / n;              // tr(Sq^{-1} Sp)
        float Bt = v3[0] + v3[1];                 // tr(Sp^{-1} Sq)
        float mq = dds - vds * vds / n;           // delta^T Sq^{-1} delta
        out[bid] = 0.25f * (Aterm + Bt - 256.f + mq + v3[2]);
    }
}

// ---------------------------------------------------------------- launch
extern "C" void kernel_launch(void* const* d_in, const int* in_sizes, int n_in,
                              void* d_out, int out_size, void* d_ws, size_t ws_size,
                              hipStream_t stream) {
    const float* wfm = (const float*)d_in[0];
    const float* wfd = (const float*)d_in[1];
    const float* sfm = (const float*)d_in[2];
    const float* sfd = (const float*)d_in[3];
    const float* W1 = (const float*)d_in[4];
    const float* B1 = (const float*)d_in[5];
    const float* W2 = (const float*)d_in[6];
    const float* B2 = (const float*)d_in[7];
    const float* W3 = (const float*)d_in[8];
    const float* B3 = (const float*)d_in[9];
    const float* W4 = (const float*)d_in[10];
    const float* B4 = (const float*)d_in[11];
    const float* lm = (const float*)d_in[12];
    const float* ldv = (const float*)d_in[13];
    float* out = (float*)d_out;
    float* ws = (float*)d_ws;

    float* wm = ws;                           // 262144
    float* wv = ws + 262144;                  // 262144
    float* sm = ws + 524288;                  // 1024
    float* sv = ws + 525312;                  // 1024
    float4* labscg = (float4*)(ws + 526336);  // 64 float4
    unsigned short* wvTg = (unsigned short*)(ws + 731392);  // 262144 bf16

    constexpr int SH_FLOATS = 19800;
    constexpr size_t SH_BYTES = SH_FLOATS * sizeof(float);   // 79200 B -> 2 blocks/CU
    (void)hipFuncSetAttribute((const void*)k4_fused,
                              hipFuncAttributeMaxDynamicSharedMemorySize,
                              (int)SH_BYTES);

    k1_gemm<<<dim3(258, 2), 256, 0, stream>>>(wfm, wfd, sfm, sfd,
                                              W1, B1, W2, B2, W3, B3, W4, B4,
                                              lm, ldv, wm, wv, sm, sv, labscg, wvTg);
    k4_fused<<<512, 256, SH_BYTES, stream>>>(wm, wv, wvTg, sm, sv, lm, ldv, labscg, out);
}